// Round 10
// baseline (449.712 us; speedup 1.0000x reference)
//
#include <hip/hip_runtime.h>
#include <hip/hip_bf16.h>

#define N_NODES 10000
#define N_EDGES 320000
#define DIN 512
#define H 256
#define NHEADS 4
#define DH 64
#define NG 64
#define OUT_DIM 512

typedef __hip_bfloat16 bf16;
typedef __attribute__((ext_vector_type(8))) short s8v;
typedef __attribute__((ext_vector_type(4))) float f4v;

// ---------- workspace layout (float offsets) ----------
static const size_t OFF_XRES  = 0;           // N*H fp32
static const size_t OFF_X1    = 2560000;     // N*H fp32
static const size_t OFF_XLB   = 5120000;     // N*H bf16
static const size_t OFF_XRB   = 6400000;     // N*H bf16
static const size_t OFF_XRESB = 7680000;     // N*H bf16
static const size_t OFF_AGGB  = 8960000;     // N*H bf16
static const size_t OFF_X1B   = 10240000;    // N*H bf16
static const size_t OFF_X2B   = 11520000;    // N*H bf16
static const size_t OFF_WPT   = 12800000;    // 512x256 bf16 (tiled)
static const size_t OFF_WRELT = 12865536;
static const size_t OFF_WROOTT= 12898304;
static const size_t OFF_WLT   = 12931072;
static const size_t OFF_WRT   = 12963840;
static const size_t OFF_WG2AT = 12996608;
static const size_t OFF_WG1AT = 13029376;    // 256x128 bf16 (tiled)
static const size_t OFF_G1    = 13045760;    // N
static const size_t OFF_G2    = 13055760;    // N
static const size_t OFF_GS1   = 13065760;    // 64
static const size_t OFF_GS2   = 13065824;    // 64
static const size_t OFF_FIN   = 13065888;    // G*768
// int offsets into (int*)ws
static const size_t IOFF_CUR  = 13120000;    // N
static const size_t IOFF_ROW  = 13130016;    // N+1
static const size_t IOFF_COL  = 13140032;    // E

__device__ __forceinline__ float gelu_f(float x) {
    return 0.5f * x * (1.0f + erff(x * 0.70710678118654752440f));
}
__device__ __forceinline__ short f2bf(float f) {
    union { float f; unsigned u; } v; v.f = f;
    unsigned r = v.u + 0x7fffu + ((v.u >> 16) & 1u);
    return (short)(r >> 16);
}
__device__ __forceinline__ float wsum64(float v) {
#pragma unroll
    for (int o = 32; o > 0; o >>= 1) v += __shfl_xor(v, o, 64);
    return v;
}
__device__ __forceinline__ float blk_sum(float v, float* s) {
#pragma unroll
    for (int o = 32; o > 0; o >>= 1) v += __shfl_xor(v, o, 64);
    int lane = threadIdx.x & 63, w = threadIdx.x >> 6;
    __syncthreads();
    if (lane == 0) s[w] = v;
    __syncthreads();
    float t = 0.f;
    int nw = blockDim.x >> 6;
    for (int i = 0; i < nw; i++) t += s[i];
    return t;
}
__device__ __forceinline__ float blk_max(float v, float* s) {
#pragma unroll
    for (int o = 32; o > 0; o >>= 1) v = fmaxf(v, __shfl_xor(v, o, 64));
    int lane = threadIdx.x & 63, w = threadIdx.x >> 6;
    __syncthreads();
    if (lane == 0) s[w] = v;
    __syncthreads();
    float t = s[0];
    int nw = blockDim.x >> 6;
    for (int i = 1; i < nw; i++) t = fmaxf(t, s[i]);
    return t;
}
__device__ __forceinline__ int lowerb(const int* b, int n, int v) {
    int lo = 0, hi = n;
    while (lo < hi) { int mid = (lo + hi) >> 1; if (b[mid] < v) lo = mid + 1; else hi = mid; }
    return lo;
}

// ---------- CSR build ----------
__global__ void k_count(const int* __restrict__ dst, int* __restrict__ deg) {
    int e = blockIdx.x * blockDim.x + threadIdx.x;
    if (e < N_EDGES) atomicAdd(&deg[dst[e]], 1);
}
__global__ void k_scan(const int* __restrict__ deg, int* __restrict__ row) {
    __shared__ int part[1024];
    int t = threadIdx.x;
    int base = t * 10;
    int v[10];
    int s = 0;
#pragma unroll
    for (int i = 0; i < 10; i++) {
        int idx = base + i;
        v[i] = (idx < N_NODES) ? deg[idx] : 0;
        s += v[i];
    }
    part[t] = s;
    __syncthreads();
    for (int off = 1; off < 1024; off <<= 1) {
        int x = (t >= off) ? part[t - off] : 0;
        __syncthreads();
        part[t] += x;
        __syncthreads();
    }
    int run = (t == 0) ? 0 : part[t - 1];
#pragma unroll
    for (int i = 0; i < 10; i++) {
        int idx = base + i;
        if (idx < N_NODES) row[idx] = run;
        run += v[i];
    }
    if (t == 1023) row[N_NODES] = part[1023];
}
__global__ void k_fill(const int* __restrict__ src, const int* __restrict__ dst,
                       const int* __restrict__ row, int* __restrict__ cur,
                       int* __restrict__ col) {
    int e = blockIdx.x * blockDim.x + threadIdx.x;
    if (e >= N_EDGES) return;
    int d = dst[e];
    int pos = atomicAdd(&cur[d], 1);
    col[row[d] + pos] = src[e];
}

// ---------- weight transpose+cast: W[K][N] fp32 -> Wt tiled [K/32][N][32] bf16 ----------
__global__ void k_twall(const float* Wp, const float* Wrel, const float* Wroot,
                        const float* Wl, const float* Wr, const float* Wg2a,
                        const float* Wg1a, short* WpT, short* WrelT, short* WrootT,
                        short* WlT, short* WrT, short* Wg2aT, short* Wg1aT) {
    const float* W; short* out; int K, N;
    switch (blockIdx.z) {
        case 0: W = Wp;   out = WpT;   K = 512; N = 256; break;
        case 1: W = Wrel; out = WrelT; K = 256; N = 256; break;
        case 2: W = Wroot;out = WrootT;K = 256; N = 256; break;
        case 3: W = Wl;   out = WlT;   K = 256; N = 256; break;
        case 4: W = Wr;   out = WrT;   K = 256; N = 256; break;
        case 5: W = Wg2a; out = Wg2aT; K = 256; N = 256; break;
        default:W = Wg1a; out = Wg1aT; K = 256; N = 128; break;
    }
    int c = blockIdx.x, nb = blockIdx.y * 64;
    if (c * 32 >= K || nb >= N) return;
    __shared__ float t[32][65];
    int tid = threadIdx.x;
    int col = tid & 63, kr = tid >> 6;
#pragma unroll
    for (int i = 0; i < 8; i++) {
        int kk = kr * 8 + i;
        t[kk][col] = W[(size_t)(c * 32 + kk) * N + nb + col];
    }
    __syncthreads();
#pragma unroll
    for (int i = 0; i < 8; i++) {
        int idx = tid + i * 256;
        int nn = idx >> 5, kk = idx & 31;
        out[(size_t)c * N * 32 + (size_t)(nb + nn) * 32 + kk] = f2bf(t[kk][nn]);
    }
}

// ---------- MFMA GEMM building blocks ----------
__device__ __forceinline__ void stage_a(const short* __restrict__ A, int nb, int c,
                                        short* sA) {
    int t = threadIdx.x;
    if (t < 128) {
        int r = t >> 2, part = t & 3;
        int n = nb + r;
        s8v v = {};
        if (n < N_NODES) v = *(const s8v*)(A + (size_t)n * 256 + c * 32 + part * 8);
        *(s8v*)(sA + r * 40 + part * 8) = v;
    }
}
__device__ __forceinline__ void stage_wt(const short* __restrict__ Wt, int c, short* sW) {
    int t = threadIdx.x;
    const s8v* src = (const s8v*)(Wt + (size_t)c * 8192);
#pragma unroll
    for (int i = 0; i < 4; i++) {
        int u = t + i * 256;
        *(s8v*)(sW + (u >> 2) * 40 + (u & 3) * 8) = src[u];
    }
}
__device__ __forceinline__ void stage_wt128(const short* __restrict__ Wt, int c, short* sW) {
    int t = threadIdx.x;
    const s8v* src = (const s8v*)(Wt + (size_t)c * 4096);
#pragma unroll
    for (int i = 0; i < 2; i++) {
        int u = t + i * 256;
        *(s8v*)(sW + (u >> 2) * 40 + (u & 3) * 8) = src[u];
    }
}
__device__ __forceinline__ void mfma_step(const short* sA, const short* sW,
                                          f4v (&acc)[2][4]) {
    int lane = threadIdx.x & 63, wv = threadIdx.x >> 6;
    int m = lane & 15, quad = lane >> 4;
    s8v af0 = *(const s8v*)(sA + m * 40 + quad * 8);
    s8v af1 = *(const s8v*)(sA + (16 + m) * 40 + quad * 8);
#pragma unroll
    for (int ctl = 0; ctl < 4; ctl++) {
        s8v bf = *(const s8v*)(sW + (wv * 64 + ctl * 16 + m) * 40 + quad * 8);
        acc[0][ctl] = __builtin_amdgcn_mfma_f32_16x16x32_bf16(af0, bf, acc[0][ctl], 0, 0, 0);
        acc[1][ctl] = __builtin_amdgcn_mfma_f32_16x16x32_bf16(af1, bf, acc[1][ctl], 0, 0, 0);
    }
}
__device__ __forceinline__ void mfma_step128(const short* sA, const short* sW,
                                             f4v (&acc)[2][2]) {
    int lane = threadIdx.x & 63, wv = threadIdx.x >> 6;
    int m = lane & 15, quad = lane >> 4;
    s8v af0 = *(const s8v*)(sA + m * 40 + quad * 8);
    s8v af1 = *(const s8v*)(sA + (16 + m) * 40 + quad * 8);
#pragma unroll
    for (int ctl = 0; ctl < 2; ctl++) {
        s8v bf = *(const s8v*)(sW + (wv * 32 + ctl * 16 + m) * 40 + quad * 8);
        acc[0][ctl] = __builtin_amdgcn_mfma_f32_16x16x32_bf16(af0, bf, acc[0][ctl], 0, 0, 0);
        acc[1][ctl] = __builtin_amdgcn_mfma_f32_16x16x32_bf16(af1, bf, acc[1][ctl], 0, 0, 0);
    }
}
__device__ __forceinline__ void dump_c(const f4v (&acc)[2][4], float* C) {
    int lane = threadIdx.x & 63, wv = threadIdx.x >> 6;
    int m = lane & 15, quad = lane >> 4;
#pragma unroll
    for (int r = 0; r < 2; r++)
#pragma unroll
        for (int ctl = 0; ctl < 4; ctl++)
#pragma unroll
            for (int reg = 0; reg < 4; reg++)
                C[(r * 16 + quad * 4 + reg) * 264 + wv * 64 + ctl * 16 + m] = acc[r][ctl][reg];
}
__device__ __forceinline__ void dump_c128(const f4v (&acc)[2][2], float* C) {
    int lane = threadIdx.x & 63, wv = threadIdx.x >> 6;
    int m = lane & 15, quad = lane >> 4;
#pragma unroll
    for (int r = 0; r < 2; r++)
#pragma unroll
        for (int ctl = 0; ctl < 2; ctl++)
#pragma unroll
            for (int reg = 0; reg < 4; reg++)
                C[(r * 16 + quad * 4 + reg) * 136 + wv * 32 + ctl * 16 + m] = acc[r][ctl][reg];
}

// ---------- kernels ----------

// x_res = LN(gelu(LN_in(x) @ Wp + bp))
__global__ __launch_bounds__(256) void k_proj(
        const float* __restrict__ x, const float* __restrict__ g0,
        const float* __restrict__ b0, const short* __restrict__ WpT,
        const float* __restrict__ bp, const float* __restrict__ lg,
        const float* __restrict__ lb, float* __restrict__ xres,
        bf16* __restrict__ xresb) {
    __shared__ short sA[32 * 40];
    __shared__ float uC[32 * 264];      // union: sW (20 KB) overlays C (33 KB)
    short* sW = (short*)uC;
    __shared__ float sm_mean[32], sm_invs[32];
    int nb = blockIdx.x * 32;
    int lane = threadIdx.x & 63, tn = threadIdx.x >> 6;
#pragma unroll
    for (int i = 0; i < 8; i++) {
        int r = tn * 8 + i;
        int n = nb + r;
        float s = 0.f, q = 0.f;
        if (n < N_NODES) {
#pragma unroll
            for (int j = 0; j < 8; j++) {
                float v = x[(size_t)n * DIN + lane + j * 64];
                s += v; q += v * v;
            }
        }
        s = wsum64(s); q = wsum64(q);
        float m = s * (1.0f / DIN);
        float var = q * (1.0f / DIN) - m * m;
        if (lane == 0) { sm_mean[r] = m; sm_invs[r] = rsqrtf(var + 1e-5f); }
    }
    __syncthreads();
    f4v acc[2][4] = {};
    for (int c = 0; c < 16; c++) {
        int t = threadIdx.x;
        if (t < 128) {
            int r = t >> 2, part = t & 3;
            int n = nb + r;
            short tmp[8];
            if (n < N_NODES) {
                int k = c * 32 + part * 8;
                float mm = sm_mean[r], is = sm_invs[r];
#pragma unroll
                for (int jj = 0; jj < 8; jj++) {
                    float v = (x[(size_t)n * DIN + k + jj] - mm) * is * g0[k + jj] + b0[k + jj];
                    tmp[jj] = f2bf(v);
                }
            } else {
#pragma unroll
                for (int jj = 0; jj < 8; jj++) tmp[jj] = 0;
            }
            *(s8v*)(sA + r * 40 + part * 8) = *(s8v*)tmp;
        }
        stage_wt(WpT, c, sW);
        __syncthreads();
        mfma_step(sA, sW, acc);
        __syncthreads();
    }
    dump_c(acc, uC);
    __syncthreads();
    float bp4[4], lg4[4], lb4[4];
#pragma unroll
    for (int j = 0; j < 4; j++) {
        bp4[j] = bp[lane + j * 64];
        lg4[j] = lg[lane + j * 64];
        lb4[j] = lb[lane + j * 64];
    }
#pragma unroll
    for (int i = 0; i < 8; i++) {
        int row = tn * 8 + i;
        float v[4];
#pragma unroll
        for (int j = 0; j < 4; j++) v[j] = gelu_f(uC[row * 264 + lane + j * 64] + bp4[j]);
        float m = wsum64(v[0] + v[1] + v[2] + v[3]) * (1.0f / H);
        float d[4], q = 0.f;
#pragma unroll
        for (int j = 0; j < 4; j++) { d[j] = v[j] - m; q += d[j] * d[j]; }
        float inv = rsqrtf(wsum64(q) * (1.0f / H) + 1e-5f);
        int n = nb + row;
        if (n < N_NODES) {
#pragma unroll
            for (int j = 0; j < 4; j++) {
                float r = d[j] * inv * lg4[j] + lb4[j];
                xres[(size_t)n * H + lane + j * 64] = r;
                xresb[(size_t)n * H + lane + j * 64] = __float2bfloat16(r);
            }
        }
    }
}

// aggb[n] = bf16( sum_{s in nbrs(n)} xresb[s] )
__global__ void k_gather(const int* __restrict__ row, const int* __restrict__ col,
                         const bf16* __restrict__ xresb, bf16* __restrict__ aggb) {
    int n = blockIdx.x, tid = threadIdx.x;
    int i = row[n], e0 = row[n + 1];
    float a = 0.f;
    for (; i + 7 < e0; i += 8) {
        int c0 = col[i], c1 = col[i + 1], c2 = col[i + 2], c3 = col[i + 3];
        int c4 = col[i + 4], c5 = col[i + 5], c6 = col[i + 6], c7 = col[i + 7];
        a += __bfloat162float(xresb[(size_t)c0 * H + tid])
           + __bfloat162float(xresb[(size_t)c1 * H + tid])
           + __bfloat162float(xresb[(size_t)c2 * H + tid])
           + __bfloat162float(xresb[(size_t)c3 * H + tid])
           + __bfloat162float(xresb[(size_t)c4 * H + tid])
           + __bfloat162float(xresb[(size_t)c5 * H + tid])
           + __bfloat162float(xresb[(size_t)c6 * H + tid])
           + __bfloat162float(xresb[(size_t)c7 * H + tid]);
    }
    for (; i < e0; i++) a += __bfloat162float(xresb[(size_t)col[i] * H + tid]);
    aggb[(size_t)n * H + tid] = __float2bfloat16(a);
}

// x1 = LN(gelu(agg@Wrel + xres@Wroot + brel)) + xres ; also x1b bf16
__global__ __launch_bounds__(256) void k_conv(
        const short* __restrict__ aggb, const short* __restrict__ xresbS,
        const float* __restrict__ xres, const short* __restrict__ WrelT,
        const short* __restrict__ WrootT, const float* __restrict__ brel,
        const float* __restrict__ n1g, const float* __restrict__ n1b,
        float* __restrict__ x1, bf16* __restrict__ x1b) {
    __shared__ short sA1[32 * 40];
    __shared__ short sA2[32 * 40];
    __shared__ float uC[32 * 264 + 2048];   // union: sW1+sW2 / C
    short* sW1 = (short*)uC;
    short* sW2 = sW1 + 10240;
    int nb = blockIdx.x * 32;
    int lane = threadIdx.x & 63, tn = threadIdx.x >> 6;
    f4v acc[2][4] = {};
    for (int c = 0; c < 8; c++) {
        stage_a(aggb, nb, c, sA1);
        stage_a(xresbS, nb, c, sA2);
        stage_wt(WrelT, c, sW1);
        stage_wt(WrootT, c, sW2);
        __syncthreads();
        mfma_step(sA1, sW1, acc);
        mfma_step(sA2, sW2, acc);
        __syncthreads();
    }
    dump_c(acc, uC);
    __syncthreads();
    float bb[4], gg[4], nb4[4];
#pragma unroll
    for (int j = 0; j < 4; j++) {
        bb[j] = brel[lane + j * 64];
        gg[j] = n1g[lane + j * 64];
        nb4[j] = n1b[lane + j * 64];
    }
#pragma unroll
    for (int i = 0; i < 8; i++) {
        int row = tn * 8 + i;
        float v[4];
#pragma unroll
        for (int j = 0; j < 4; j++) v[j] = gelu_f(uC[row * 264 + lane + j * 64] + bb[j]);
        float m = wsum64(v[0] + v[1] + v[2] + v[3]) * (1.0f / H);
        float d[4], q = 0.f;
#pragma unroll
        for (int j = 0; j < 4; j++) { d[j] = v[j] - m; q += d[j] * d[j]; }
        float inv = rsqrtf(wsum64(q) * (1.0f / H) + 1e-5f);
        int n = nb + row;
        if (n < N_NODES) {
#pragma unroll
            for (int j = 0; j < 4; j++) {
                size_t idx = (size_t)n * H + lane + j * 64;
                float r = d[j] * inv * gg[j] + nb4[j] + xres[idx];
                x1[idx] = r;
                x1b[idx] = __float2bfloat16(r);
            }
        }
    }
}

// xl = x1@Wl + bl ; xr = x1@Wr + br  (bf16 outs, direct frag stores)
__global__ __launch_bounds__(256) void k_lin2(
        const short* __restrict__ x1b, const short* __restrict__ WlT,
        const short* __restrict__ WrT, const float* __restrict__ bl,
        const float* __restrict__ br, bf16* __restrict__ xlb,
        bf16* __restrict__ xrb) {
    __shared__ short sA[32 * 40];
    __shared__ short sW1[256 * 40];
    __shared__ short sW2[256 * 40];
    int nb = blockIdx.x * 32;
    f4v accL[2][4] = {};
    f4v accR[2][4] = {};
    for (int c = 0; c < 8; c++) {
        stage_a(x1b, nb, c, sA);
        stage_wt(WlT, c, sW1);
        stage_wt(WrT, c, sW2);
        __syncthreads();
        mfma_step(sA, sW1, accL);
        mfma_step(sA, sW2, accR);
        __syncthreads();
    }
    int lane = threadIdx.x & 63, wv = threadIdx.x >> 6;
    int m = lane & 15, quad = lane >> 4;
#pragma unroll
    for (int ctl = 0; ctl < 4; ctl++) {
        int colx = wv * 64 + ctl * 16 + m;
        float blv = bl[colx], brv = br[colx];
#pragma unroll
        for (int r = 0; r < 2; r++)
#pragma unroll
            for (int reg = 0; reg < 4; reg++) {
                int n = nb + r * 16 + quad * 4 + reg;
                if (n < N_NODES) {
                    xlb[(size_t)n * H + colx] = __float2bfloat16(accL[r][ctl][reg] + blv);
                    xrb[(size_t)n * H + colx] = __float2bfloat16(accR[r][ctl][reg] + brv);
                }
            }
    }
}

// fused GATv2 + x2 epilogue — single-pass register-resident flash softmax.
// Block = node; wave = head; lanes = (ei in 0..15, dc in 0..3); chunk = 16 edges.
// Each lane keeps its edge's 16-dim xl slice in registers and accumulates
// a-weighted partials; cross-lane reduce over ei-groups happens once at the end.
__global__ __launch_bounds__(256, 6) void k_gat(
        const int* __restrict__ row, const int* __restrict__ col,
        const bf16* __restrict__ xl, const bf16* __restrict__ xr,
        const float* __restrict__ att, const float* __restrict__ gatb,
        const float* __restrict__ n2g, const float* __restrict__ n2b,
        const float* __restrict__ x1, bf16* __restrict__ x2b) {
    __shared__ float msgbuf[NHEADS * 64];
    __shared__ float red[8];
    int n = blockIdx.x;
    int tid = threadIdx.x;
    int h = tid >> 6, lane = tid & 63;
    int ei = lane >> 2, dc = lane & 3;
    float xr16[16], att16[16];
    {
        const bf16* xrrow = xr + (size_t)n * H + h * DH + dc * 16;
        const float* attrow = att + h * DH + dc * 16;
#pragma unroll
        for (int j = 0; j < 16; j++) {
            xr16[j] = __bfloat162float(xrrow[j]);
            att16[j] = attrow[j];
        }
    }
    int rs = row[n];
    int ec = row[n + 1] - rs + 1;   // extended: index 0 = self-loop
    float m = -3.4e38f, l = 0.f;
    float acc16[16];
#pragma unroll
    for (int j = 0; j < 16; j++) acc16[j] = 0.f;
    for (int c0 = 0; c0 < ec; c0 += 16) {
        int g = c0 + ei;
        bool valid = g < ec;
        int s = (valid && g > 0) ? col[rs + g - 1] : n;
        const unsigned* xlr = (const unsigned*)(xl + (size_t)s * H + h * DH + dc * 16);
        float v[16];
        float p = 0.f;
#pragma unroll
        for (int jj = 0; jj < 8; jj++) {
            unsigned u = xlr[jj];
            float v0 = __uint_as_float((u & 0xffffu) << 16);
            float v1 = __uint_as_float(u & 0xffff0000u);
            v[2 * jj] = v0; v[2 * jj + 1] = v1;
            float a0 = v0 + xr16[2 * jj];
            float a1 = v1 + xr16[2 * jj + 1];
            a0 = (a0 > 0.f) ? a0 : 0.2f * a0;
            a1 = (a1 > 0.f) ? a1 : 0.2f * a1;
            p += a0 * att16[2 * jj] + a1 * att16[2 * jj + 1];
        }
        p += __shfl_xor(p, 1, 64);
        p += __shfl_xor(p, 2, 64);   // full logit of edge ei, in all 4 dc lanes
        if (!valid) p = -3.4e38f;
        float cm = p;
#pragma unroll
        for (int o = 4; o < 64; o <<= 1) cm = fmaxf(cm, __shfl_xor(cm, o, 64));
        float nm = fmaxf(m, cm);
        float sc = __expf(m - nm);
        float a = valid ? __expf(p - nm) : 0.f;
        l = l * sc + a;
#pragma unroll
        for (int j = 0; j < 16; j++) acc16[j] = acc16[j] * sc + a * v[j];
        m = nm;
    }
    // reduce over the 16 ei-lane groups (each edge counted once per dc group)
#pragma unroll
    for (int o = 4; o < 64; o <<= 1) {
        l += __shfl_xor(l, o, 64);
#pragma unroll
        for (int j = 0; j < 16; j++) acc16[j] += __shfl_xor(acc16[j], o, 64);
    }
    if (ei == 0) {
        float invl = 1.0f / l;
#pragma unroll
        for (int j = 0; j < 16; j++) msgbuf[h * 64 + dc * 16 + j] = acc16[j] * invl;
    }
    __syncthreads();
    // ---- fused x2 epilogue: LN(gelu(msg + gatb)) + x1 ----
    int off = tid;
    float msg = msgbuf[h * 64 + lane];
    float p = gelu_f(msg + gatb[off]);
    float sm = blk_sum(p, red) * (1.0f / H);
    float dd = p - sm;
    float vv = blk_sum(dd * dd, red) * (1.0f / H);
    float inv = rsqrtf(vv + 1e-5f);
    float r = dd * inv * n2g[off] + n2b[off] + x1[(size_t)n * H + off];
    x2b[(size_t)n * H + off] = __float2bfloat16(r);
}

// gates via MFMA
__global__ __launch_bounds__(256) void k_gates(
        const short* __restrict__ x2b, const short* __restrict__ Wg2aT,
        const short* __restrict__ Wg1aT, const float* __restrict__ bg2a,
        const float* __restrict__ Wg2b, const float* __restrict__ bg2b,
        const float* __restrict__ bg1a, const float* __restrict__ Wg1b,
        const float* __restrict__ bg1b, float* __restrict__ gate1,
        float* __restrict__ gate2) {
    __shared__ short sA[32 * 40];
    __shared__ float u[12800];
    short* sW2g = (short*)u;
    short* sW1g = sW2g + 10240;
    float* C2 = u;
    float* C1 = u + 8448;
    int nb = blockIdx.x * 32;
    int lane = threadIdx.x & 63, tn = threadIdx.x >> 6;
    f4v acc2[2][4] = {};
    f4v acc1[2][2] = {};
    for (int c = 0; c < 8; c++) {
        stage_a(x2b, nb, c, sA);
        stage_wt(Wg2aT, c, sW2g);
        stage_wt128(Wg1aT, c, sW1g);
        __syncthreads();
        mfma_step(sA, sW2g, acc2);
        mfma_step128(sA, sW1g, acc1);
        __syncthreads();
    }
    dump_c(acc2, C2);
    dump_c128(acc1, C1);
    __syncthreads();
    float wb2[4], b2[4], wb1[2], b1[2];
#pragma unroll
    for (int j = 0; j < 4; j++) { wb2[j] = Wg2b[lane + j * 64]; b2[j] = bg2a[lane + j * 64]; }
#pragma unroll
    for (int j = 0; j < 2; j++) { wb1[j] = Wg1b[lane + j * 64]; b1[j] = bg1a[lane + j * 64]; }
    float c2c = bg2b[0], c1c = bg1b[0];
#pragma unroll
    for (int i = 0; i < 8; i++) {
        int rowi = tn * 8 + i;
        float s2 = 0.f;
#pragma unroll
        for (int j = 0; j < 4; j++) s2 += tanhf(C2[rowi * 264 + lane + j * 64] + b2[j]) * wb2[j];
        s2 = wsum64(s2);
        float s1 = 0.f;
#pragma unroll
        for (int j = 0; j < 2; j++) s1 += tanhf(C1[rowi * 136 + lane + j * 64] + b1[j]) * wb1[j];
        s1 = wsum64(s1);
        int n = nb + rowi;
        if (lane == 0 && n < N_NODES) { gate2[n] = s2 + c2c; gate1[n] = s1 + c1c; }
    }
}

// per-group pooling (x2 read as bf16)
__global__ void k_group(const int* __restrict__ batch, const bf16* __restrict__ x2b,
                        const float* __restrict__ xres, const float* __restrict__ g1,
                        const float* __restrict__ g2, float* __restrict__ gs1,
                        float* __restrict__ gs2, float* __restrict__ fin) {
    __shared__ float red[8];
    __shared__ int seb[2];
    int g = blockIdx.x >> 2, part = blockIdx.x & 3;
    int tid = threadIdx.x;
    if (tid == 0) {
        seb[0] = lowerb(batch, N_NODES, g);
        seb[1] = lowerb(batch, N_NODES, g + 1);
    }
    __syncthreads();
    int s = seb[0], e = seb[1];
    if (e <= s) return;
    float m1 = -3.4e38f, m2 = -3.4e38f;
    for (int i = s + tid; i < e; i += 256) {
        m1 = fmaxf(m1, g1[i]);
        m2 = fmaxf(m2, g2[i]);
    }
    m1 = blk_max(m1, red);
    m2 = blk_max(m2, red);
    int deg = e - s;
    int q0 = s + deg * part / 4, q1 = s + deg * (part + 1) / 4;
    float s1 = 0.f, s2 = 0.f, e1 = 0.f, e2 = 0.f, gr = 0.f;
    for (int i = q0; i < q1; i++) {
        float w1 = __expf(g1[i] - m1);
        float w2 = __expf(g2[i] - m2);
        float xv = __bfloat162float(x2b[(size_t)i * H + tid]);
        float rv = xres[(size_t)i * H + tid];
        s1 += w1; s2 += w2;
        e1 += w1 * xv; e2 += w2 * xv; gr += rv;
    }
    if (q1 > q0) {
        atomicAdd(&fin[(size_t)g * 768 + tid], e1);
        atomicAdd(&fin[(size_t)g * 768 + 256 + tid], e2);
        atomicAdd(&fin[(size_t)g * 768 + 512 + tid], gr);
        if (tid == 0) { atomicAdd(&gs1[g], s1); atomicAdd(&gs2[g], s2); }
    }
}

// out = gelu([emb1|emb2|gres] @ Wo + bo) * bn — grid (NG, 8)
__global__ __launch_bounds__(256) void k_final(
        const int* __restrict__ batch, const float* __restrict__ fin,
        const float* __restrict__ gs1, const float* __restrict__ gs2,
        const float* __restrict__ Wo, const float* __restrict__ bo,
        const float* __restrict__ bng, const float* __restrict__ bnb,
        float* __restrict__ out) {
    __shared__ float fl[768];
    __shared__ float part[4][64];
    __shared__ int seb[2];
    int g = blockIdx.x, oc = blockIdx.y;
    int tid = threadIdx.x, lane = tid & 63, wv = tid >> 6;
    if (tid == 0) {
        seb[0] = lowerb(batch, N_NODES, g);
        seb[1] = lowerb(batch, N_NODES, g + 1);
    }
    __syncthreads();
    float c = fmaxf((float)(seb[1] - seb[0]), 1.0f);
    float s1 = gs1[g], s2 = gs2[g];
    fl[tid]       = (s1 > 0.f) ? fin[(size_t)g * 768 + tid] / s1 : 0.f;
    fl[256 + tid] = (s2 > 0.f) ? fin[(size_t)g * 768 + 256 + tid] / s2 : 0.f;
    fl[512 + tid] = fin[(size_t)g * 768 + 512 + tid] / c;
    __syncthreads();
    int o = oc * 64 + lane;
    float acc = 0.f;
    int k0 = wv * 192;
    for (int k = k0; k < k0 + 192; k += 8) {
#pragma unroll
        for (int j = 0; j < 8; j++)
            acc += fl[k + j] * Wo[(size_t)(k + j) * OUT_DIM + o];
    }
    part[wv][lane] = acc;
    __syncthreads();
    if (wv == 0) {
        float t = part[0][lane] + part[1][lane] + part[2][lane] + part[3][lane] + bo[o];
        float val = gelu_f(t);
        out[(size_t)g * OUT_DIM + o] = val * 0.9999950000374997f * bng[o] + bnb[o];
    }
}

extern "C" void kernel_launch(void* const* d_in, const int* in_sizes, int n_in,
                              void* d_out, int out_size, void* d_ws, size_t ws_size,
                              hipStream_t stream) {
    const float* x     = (const float*)d_in[0];
    const int*   ei    = (const int*)d_in[1];
    const int*   batch = (const int*)d_in[2];
    const float* ln_in_g = (const float*)d_in[3];
    const float* ln_in_b = (const float*)d_in[4];
    const float* Wp    = (const float*)d_in[5];
    const float* bp    = (const float*)d_in[6];
    const float* lnp_g = (const float*)d_in[7];
    const float* lnp_b = (const float*)d_in[8];
    const float* Wrel  = (const float*)d_in[9];
    const float* brel  = (const float*)d_in[10];
    const float* Wroot = (const float*)d_in[11];
    const float* n1_g  = (const float*)d_in[12];
    const float* n1_b  = (const float*)d_in[13];
    const float* Wl    = (const float*)d_in[14];
    const float* bl    = (const float*)d_in[15];
    const float* Wr    = (const float*)d_in[16];
    const float* br    = (const float*)d_in[17];
    const float* att   = (const float*)d_in[18];
    const float* gat_b = (const float*)d_in[19];
    const float* n2_g  = (const float*)d_in[20];
    const float* n2_b  = (const float*)d_in[21];
    const float* Wg1a  = (const float*)d_in[22];
    const float* bg1a  = (const float*)d_in[23];
    const float* Wg1b  = (const float*)d_in[24];
    const float* bg1b  = (const float*)d_in[25];
    const float* Wg2a  = (const float*)d_in[26];
    const float* bg2a  = (const float*)d_in[27];
    const float* Wg2b  = (const float*)d_in[28];
    const float* bg2b  = (const float*)d_in[29];
    const float* Wo    = (const float*)d_in[30];
    const float* bo    = (const float*)d_in[31];
    const float* bn_g  = (const float*)d_in[32];
    const float* bn_b  = (const float*)d_in[33];

    float* ws = (float*)d_ws;
    int* wsi = (int*)d_ws;
    const int* src = ei;
    const int* dst = ei + N_EDGES;
    int* cur = wsi + IOFF_CUR;
    int* row = wsi + IOFF_ROW;
    int* col = wsi + IOFF_COL;
    short* WpT    = (short*)(ws + OFF_WPT);
    short* WrelT  = (short*)(ws + OFF_WRELT);
    short* WrootT = (short*)(ws + OFF_WROOTT);
    short* WlT    = (short*)(ws + OFF_WLT);
    short* WrT    = (short*)(ws + OFF_WRT);
    short* Wg2aT  = (short*)(ws + OFF_WG2AT);
    short* Wg1aT  = (short*)(ws + OFF_WG1AT);
    bf16* xlb   = (bf16*)(ws + OFF_XLB);
    bf16* xrb   = (bf16*)(ws + OFF_XRB);
    bf16* xresb = (bf16*)(ws + OFF_XRESB);
    bf16* aggb  = (bf16*)(ws + OFF_AGGB);
    bf16* x1b   = (bf16*)(ws + OFF_X1B);
    bf16* x2b   = (bf16*)(ws + OFF_X2B);
    const int GB32 = (N_NODES + 31) / 32;  // 313

    hipMemsetAsync(cur, 0, N_NODES * sizeof(int), stream);
    hipMemsetAsync(ws + OFF_GS1, 0, (128 + (size_t)NG * 768) * sizeof(float), stream);
    k_count<<<(N_EDGES + 255) / 256, 256, 0, stream>>>(dst, cur);
    k_scan<<<1, 1024, 0, stream>>>(cur, row);
    hipMemsetAsync(cur, 0, N_NODES * sizeof(int), stream);
    k_fill<<<(N_EDGES + 255) / 256, 256, 0, stream>>>(src, dst, row, cur, col);

    k_twall<<<dim3(16, 4, 7), 256, 0, stream>>>(Wp, Wrel, Wroot, Wl, Wr, Wg2a, Wg1a,
                                                WpT, WrelT, WrootT, WlT, WrT, Wg2aT,
                                                Wg1aT);
    k_proj<<<GB32, 256, 0, stream>>>(x, ln_in_g, ln_in_b, WpT, bp, lnp_g, lnp_b,
                                     ws + OFF_XRES, xresb);
    k_gather<<<N_NODES, 256, 0, stream>>>(row, col, xresb, aggb);
    k_conv<<<GB32, 256, 0, stream>>>((const short*)aggb, (const short*)xresb,
                                     ws + OFF_XRES, WrelT, WrootT, brel, n1_g, n1_b,
                                     ws + OFF_X1, x1b);
    k_lin2<<<GB32, 256, 0, stream>>>((const short*)x1b, WlT, WrT, bl, br, xlb, xrb);
    k_gat<<<N_NODES, 256, 0, stream>>>(row, col, xlb, xrb, att, gat_b, n2_g, n2_b,
                                       ws + OFF_X1, x2b);
    k_gates<<<GB32, 256, 0, stream>>>((const short*)x2b, Wg2aT, Wg1aT, bg2a, Wg2b,
                                      bg2b, bg1a, Wg1b, bg1b, ws + OFF_G1, ws + OFF_G2);
    k_group<<<NG * 4, 256, 0, stream>>>(batch, x2b, ws + OFF_XRES, ws + OFF_G1,
                                        ws + OFF_G2, ws + OFF_GS1, ws + OFF_GS2,
                                        ws + OFF_FIN);
    k_final<<<dim3(NG, 8), 256, 0, stream>>>(batch, ws + OFF_FIN, ws + OFF_GS1,
                                             ws + OFF_GS2, Wo, bo, bn_g, bn_b,
                                             (float*)d_out);
}

// Round 12
// 393.025 us; speedup vs baseline: 1.1442x; 1.1442x over previous
//
#include <hip/hip_runtime.h>
#include <hip/hip_bf16.h>

#define N_NODES 10000
#define N_EDGES 320000
#define DIN 512
#define H 256
#define NHEADS 4
#define DH 64
#define NG 64
#define OUT_DIM 512

typedef __hip_bfloat16 bf16;
typedef __attribute__((ext_vector_type(8))) short s8v;
typedef __attribute__((ext_vector_type(4))) float f4v;

// ---------- workspace layout (float offsets) ----------
static const size_t OFF_XRES  = 0;           // N*H fp32
static const size_t OFF_X1    = 2560000;     // N*H fp32
static const size_t OFF_XLB   = 5120000;     // N*H bf16
static const size_t OFF_XRB   = 6400000;     // N*H bf16
static const size_t OFF_XRESB = 7680000;     // N*H bf16
static const size_t OFF_AGGB  = 8960000;     // N*H bf16
static const size_t OFF_X1B   = 10240000;    // N*H bf16
static const size_t OFF_X2B   = 11520000;    // N*H bf16
static const size_t OFF_WPT   = 12800000;    // 512x256 bf16 (tiled)
static const size_t OFF_WRELT = 12865536;
static const size_t OFF_WROOTT= 12898304;
static const size_t OFF_WLT   = 12931072;
static const size_t OFF_WRT   = 12963840;
static const size_t OFF_WG2AT = 12996608;
static const size_t OFF_WG1AT = 13029376;    // 256x128 bf16 (tiled)
static const size_t OFF_G1    = 13045760;    // N
static const size_t OFF_G2    = 13055760;    // N
static const size_t OFF_GS1   = 13065760;    // 64
static const size_t OFF_GS2   = 13065824;    // 64
static const size_t OFF_FIN   = 13065888;    // G*768
// int offsets into (int*)ws
static const size_t IOFF_CUR  = 13120000;    // N
static const size_t IOFF_ROW  = 13130016;    // N+1
static const size_t IOFF_COL  = 13140032;    // E

__device__ __forceinline__ float gelu_f(float x) {
    return 0.5f * x * (1.0f + erff(x * 0.70710678118654752440f));
}
__device__ __forceinline__ short f2bf(float f) {
    union { float f; unsigned u; } v; v.f = f;
    unsigned r = v.u + 0x7fffu + ((v.u >> 16) & 1u);
    return (short)(r >> 16);
}
__device__ __forceinline__ float wsum64(float v) {
#pragma unroll
    for (int o = 32; o > 0; o >>= 1) v += __shfl_xor(v, o, 64);
    return v;
}
__device__ __forceinline__ float blk_sum(float v, float* s) {
#pragma unroll
    for (int o = 32; o > 0; o >>= 1) v += __shfl_xor(v, o, 64);
    int lane = threadIdx.x & 63, w = threadIdx.x >> 6;
    __syncthreads();
    if (lane == 0) s[w] = v;
    __syncthreads();
    float t = 0.f;
    int nw = blockDim.x >> 6;
    for (int i = 0; i < nw; i++) t += s[i];
    return t;
}
__device__ __forceinline__ float blk_max(float v, float* s) {
#pragma unroll
    for (int o = 32; o > 0; o >>= 1) v = fmaxf(v, __shfl_xor(v, o, 64));
    int lane = threadIdx.x & 63, w = threadIdx.x >> 6;
    __syncthreads();
    if (lane == 0) s[w] = v;
    __syncthreads();
    float t = s[0];
    int nw = blockDim.x >> 6;
    for (int i = 1; i < nw; i++) t = fmaxf(t, s[i]);
    return t;
}
__device__ __forceinline__ int lowerb(const int* b, int n, int v) {
    int lo = 0, hi = n;
    while (lo < hi) { int mid = (lo + hi) >> 1; if (b[mid] < v) lo = mid + 1; else hi = mid; }
    return lo;
}

// ---------- CSR build ----------
__global__ void k_count(const int* __restrict__ dst, int* __restrict__ deg) {
    int e = blockIdx.x * blockDim.x + threadIdx.x;
    if (e < N_EDGES) atomicAdd(&deg[dst[e]], 1);
}
__global__ void k_scan(const int* __restrict__ deg, int* __restrict__ row) {
    __shared__ int part[1024];
    int t = threadIdx.x;
    int base = t * 10;
    int v[10];
    int s = 0;
#pragma unroll
    for (int i = 0; i < 10; i++) {
        int idx = base + i;
        v[i] = (idx < N_NODES) ? deg[idx] : 0;
        s += v[i];
    }
    part[t] = s;
    __syncthreads();
    for (int off = 1; off < 1024; off <<= 1) {
        int x = (t >= off) ? part[t - off] : 0;
        __syncthreads();
        part[t] += x;
        __syncthreads();
    }
    int run = (t == 0) ? 0 : part[t - 1];
#pragma unroll
    for (int i = 0; i < 10; i++) {
        int idx = base + i;
        if (idx < N_NODES) row[idx] = run;
        run += v[i];
    }
    if (t == 1023) row[N_NODES] = part[1023];
}
__global__ void k_fill(const int* __restrict__ src, const int* __restrict__ dst,
                       const int* __restrict__ row, int* __restrict__ cur,
                       int* __restrict__ col) {
    int e = blockIdx.x * blockDim.x + threadIdx.x;
    if (e >= N_EDGES) return;
    int d = dst[e];
    int pos = atomicAdd(&cur[d], 1);
    col[row[d] + pos] = src[e];
}

// ---------- weight transpose+cast: W[K][N] fp32 -> Wt tiled [K/32][N][32] bf16 ----------
__global__ void k_twall(const float* Wp, const float* Wrel, const float* Wroot,
                        const float* Wl, const float* Wr, const float* Wg2a,
                        const float* Wg1a, short* WpT, short* WrelT, short* WrootT,
                        short* WlT, short* WrT, short* Wg2aT, short* Wg1aT) {
    const float* W; short* out; int K, N;
    switch (blockIdx.z) {
        case 0: W = Wp;   out = WpT;   K = 512; N = 256; break;
        case 1: W = Wrel; out = WrelT; K = 256; N = 256; break;
        case 2: W = Wroot;out = WrootT;K = 256; N = 256; break;
        case 3: W = Wl;   out = WlT;   K = 256; N = 256; break;
        case 4: W = Wr;   out = WrT;   K = 256; N = 256; break;
        case 5: W = Wg2a; out = Wg2aT; K = 256; N = 256; break;
        default:W = Wg1a; out = Wg1aT; K = 256; N = 128; break;
    }
    int c = blockIdx.x, nb = blockIdx.y * 64;
    if (c * 32 >= K || nb >= N) return;
    __shared__ float t[32][65];
    int tid = threadIdx.x;
    int col = tid & 63, kr = tid >> 6;
#pragma unroll
    for (int i = 0; i < 8; i++) {
        int kk = kr * 8 + i;
        t[kk][col] = W[(size_t)(c * 32 + kk) * N + nb + col];
    }
    __syncthreads();
#pragma unroll
    for (int i = 0; i < 8; i++) {
        int idx = tid + i * 256;
        int nn = idx >> 5, kk = idx & 31;
        out[(size_t)c * N * 32 + (size_t)(nb + nn) * 32 + kk] = f2bf(t[kk][nn]);
    }
}

// ---------- MFMA GEMM building blocks ----------
__device__ __forceinline__ void stage_a(const short* __restrict__ A, int nb, int c,
                                        short* sA) {
    int t = threadIdx.x;
    if (t < 128) {
        int r = t >> 2, part = t & 3;
        int n = nb + r;
        s8v v = {};
        if (n < N_NODES) v = *(const s8v*)(A + (size_t)n * 256 + c * 32 + part * 8);
        *(s8v*)(sA + r * 40 + part * 8) = v;
    }
}
__device__ __forceinline__ void stage_wt(const short* __restrict__ Wt, int c, short* sW) {
    int t = threadIdx.x;
    const s8v* src = (const s8v*)(Wt + (size_t)c * 8192);
#pragma unroll
    for (int i = 0; i < 4; i++) {
        int u = t + i * 256;
        *(s8v*)(sW + (u >> 2) * 40 + (u & 3) * 8) = src[u];
    }
}
__device__ __forceinline__ void stage_wt128(const short* __restrict__ Wt, int c, short* sW) {
    int t = threadIdx.x;
    const s8v* src = (const s8v*)(Wt + (size_t)c * 4096);
#pragma unroll
    for (int i = 0; i < 2; i++) {
        int u = t + i * 256;
        *(s8v*)(sW + (u >> 2) * 40 + (u & 3) * 8) = src[u];
    }
}
__device__ __forceinline__ void mfma_step(const short* sA, const short* sW,
                                          f4v (&acc)[2][4]) {
    int lane = threadIdx.x & 63, wv = threadIdx.x >> 6;
    int m = lane & 15, quad = lane >> 4;
    s8v af0 = *(const s8v*)(sA + m * 40 + quad * 8);
    s8v af1 = *(const s8v*)(sA + (16 + m) * 40 + quad * 8);
#pragma unroll
    for (int ctl = 0; ctl < 4; ctl++) {
        s8v bf = *(const s8v*)(sW + (wv * 64 + ctl * 16 + m) * 40 + quad * 8);
        acc[0][ctl] = __builtin_amdgcn_mfma_f32_16x16x32_bf16(af0, bf, acc[0][ctl], 0, 0, 0);
        acc[1][ctl] = __builtin_amdgcn_mfma_f32_16x16x32_bf16(af1, bf, acc[1][ctl], 0, 0, 0);
    }
}
__device__ __forceinline__ void mfma_step128(const short* sA, const short* sW,
                                             f4v (&acc)[2][2]) {
    int lane = threadIdx.x & 63, wv = threadIdx.x >> 6;
    int m = lane & 15, quad = lane >> 4;
    s8v af0 = *(const s8v*)(sA + m * 40 + quad * 8);
    s8v af1 = *(const s8v*)(sA + (16 + m) * 40 + quad * 8);
#pragma unroll
    for (int ctl = 0; ctl < 2; ctl++) {
        s8v bf = *(const s8v*)(sW + (wv * 32 + ctl * 16 + m) * 40 + quad * 8);
        acc[0][ctl] = __builtin_amdgcn_mfma_f32_16x16x32_bf16(af0, bf, acc[0][ctl], 0, 0, 0);
        acc[1][ctl] = __builtin_amdgcn_mfma_f32_16x16x32_bf16(af1, bf, acc[1][ctl], 0, 0, 0);
    }
}
__device__ __forceinline__ void dump_c(const f4v (&acc)[2][4], float* C) {
    int lane = threadIdx.x & 63, wv = threadIdx.x >> 6;
    int m = lane & 15, quad = lane >> 4;
#pragma unroll
    for (int r = 0; r < 2; r++)
#pragma unroll
        for (int ctl = 0; ctl < 4; ctl++)
#pragma unroll
            for (int reg = 0; reg < 4; reg++)
                C[(r * 16 + quad * 4 + reg) * 264 + wv * 64 + ctl * 16 + m] = acc[r][ctl][reg];
}
__device__ __forceinline__ void dump_c128(const f4v (&acc)[2][2], float* C) {
    int lane = threadIdx.x & 63, wv = threadIdx.x >> 6;
    int m = lane & 15, quad = lane >> 4;
#pragma unroll
    for (int r = 0; r < 2; r++)
#pragma unroll
        for (int ctl = 0; ctl < 2; ctl++)
#pragma unroll
            for (int reg = 0; reg < 4; reg++)
                C[(r * 16 + quad * 4 + reg) * 136 + wv * 32 + ctl * 16 + m] = acc[r][ctl][reg];
}

// ---------- kernels ----------

// x_res = LN(gelu(LN_in(x) @ Wp + bp))
__global__ __launch_bounds__(256) void k_proj(
        const float* __restrict__ x, const float* __restrict__ g0,
        const float* __restrict__ b0, const short* __restrict__ WpT,
        const float* __restrict__ bp, const float* __restrict__ lg,
        const float* __restrict__ lb, float* __restrict__ xres,
        bf16* __restrict__ xresb) {
    __shared__ short sA[32 * 40];
    __shared__ float uC[32 * 264];      // union: sW (20 KB) overlays C (33 KB)
    short* sW = (short*)uC;
    __shared__ float sm_mean[32], sm_invs[32];
    int nb = blockIdx.x * 32;
    int lane = threadIdx.x & 63, tn = threadIdx.x >> 6;
#pragma unroll
    for (int i = 0; i < 8; i++) {
        int r = tn * 8 + i;
        int n = nb + r;
        float s = 0.f, q = 0.f;
        if (n < N_NODES) {
#pragma unroll
            for (int j = 0; j < 8; j++) {
                float v = x[(size_t)n * DIN + lane + j * 64];
                s += v; q += v * v;
            }
        }
        s = wsum64(s); q = wsum64(q);
        float m = s * (1.0f / DIN);
        float var = q * (1.0f / DIN) - m * m;
        if (lane == 0) { sm_mean[r] = m; sm_invs[r] = rsqrtf(var + 1e-5f); }
    }
    __syncthreads();
    f4v acc[2][4] = {};
    for (int c = 0; c < 16; c++) {
        int t = threadIdx.x;
        if (t < 128) {
            int r = t >> 2, part = t & 3;
            int n = nb + r;
            short tmp[8];
            if (n < N_NODES) {
                int k = c * 32 + part * 8;
                float mm = sm_mean[r], is = sm_invs[r];
#pragma unroll
                for (int jj = 0; jj < 8; jj++) {
                    float v = (x[(size_t)n * DIN + k + jj] - mm) * is * g0[k + jj] + b0[k + jj];
                    tmp[jj] = f2bf(v);
                }
            } else {
#pragma unroll
                for (int jj = 0; jj < 8; jj++) tmp[jj] = 0;
            }
            *(s8v*)(sA + r * 40 + part * 8) = *(s8v*)tmp;
        }
        stage_wt(WpT, c, sW);
        __syncthreads();
        mfma_step(sA, sW, acc);
        __syncthreads();
    }
    dump_c(acc, uC);
    __syncthreads();
    float bp4[4], lg4[4], lb4[4];
#pragma unroll
    for (int j = 0; j < 4; j++) {
        bp4[j] = bp[lane + j * 64];
        lg4[j] = lg[lane + j * 64];
        lb4[j] = lb[lane + j * 64];
    }
#pragma unroll
    for (int i = 0; i < 8; i++) {
        int row = tn * 8 + i;
        float v[4];
#pragma unroll
        for (int j = 0; j < 4; j++) v[j] = gelu_f(uC[row * 264 + lane + j * 64] + bp4[j]);
        float m = wsum64(v[0] + v[1] + v[2] + v[3]) * (1.0f / H);
        float d[4], q = 0.f;
#pragma unroll
        for (int j = 0; j < 4; j++) { d[j] = v[j] - m; q += d[j] * d[j]; }
        float inv = rsqrtf(wsum64(q) * (1.0f / H) + 1e-5f);
        int n = nb + row;
        if (n < N_NODES) {
#pragma unroll
            for (int j = 0; j < 4; j++) {
                float r = d[j] * inv * lg4[j] + lb4[j];
                xres[(size_t)n * H + lane + j * 64] = r;
                xresb[(size_t)n * H + lane + j * 64] = __float2bfloat16(r);
            }
        }
    }
}

// aggb[n] = bf16( sum_{s in nbrs(n)} xresb[s] )
__global__ void k_gather(const int* __restrict__ row, const int* __restrict__ col,
                         const bf16* __restrict__ xresb, bf16* __restrict__ aggb) {
    int n = blockIdx.x, tid = threadIdx.x;
    int i = row[n], e0 = row[n + 1];
    float a = 0.f;
    for (; i + 7 < e0; i += 8) {
        int c0 = col[i], c1 = col[i + 1], c2 = col[i + 2], c3 = col[i + 3];
        int c4 = col[i + 4], c5 = col[i + 5], c6 = col[i + 6], c7 = col[i + 7];
        a += __bfloat162float(xresb[(size_t)c0 * H + tid])
           + __bfloat162float(xresb[(size_t)c1 * H + tid])
           + __bfloat162float(xresb[(size_t)c2 * H + tid])
           + __bfloat162float(xresb[(size_t)c3 * H + tid])
           + __bfloat162float(xresb[(size_t)c4 * H + tid])
           + __bfloat162float(xresb[(size_t)c5 * H + tid])
           + __bfloat162float(xresb[(size_t)c6 * H + tid])
           + __bfloat162float(xresb[(size_t)c7 * H + tid]);
    }
    for (; i < e0; i++) a += __bfloat162float(xresb[(size_t)col[i] * H + tid]);
    aggb[(size_t)n * H + tid] = __float2bfloat16(a);
}

// x1 = LN(gelu(agg@Wrel + xres@Wroot + brel)) + xres ; also x1b bf16
__global__ __launch_bounds__(256) void k_conv(
        const short* __restrict__ aggb, const short* __restrict__ xresbS,
        const float* __restrict__ xres, const short* __restrict__ WrelT,
        const short* __restrict__ WrootT, const float* __restrict__ brel,
        const float* __restrict__ n1g, const float* __restrict__ n1b,
        float* __restrict__ x1, bf16* __restrict__ x1b) {
    __shared__ short sA1[32 * 40];
    __shared__ short sA2[32 * 40];
    __shared__ float uC[32 * 264 + 2048];   // union: sW1+sW2 / C
    short* sW1 = (short*)uC;
    short* sW2 = sW1 + 10240;
    int nb = blockIdx.x * 32;
    int lane = threadIdx.x & 63, tn = threadIdx.x >> 6;
    f4v acc[2][4] = {};
    for (int c = 0; c < 8; c++) {
        stage_a(aggb, nb, c, sA1);
        stage_a(xresbS, nb, c, sA2);
        stage_wt(WrelT, c, sW1);
        stage_wt(WrootT, c, sW2);
        __syncthreads();
        mfma_step(sA1, sW1, acc);
        mfma_step(sA2, sW2, acc);
        __syncthreads();
    }
    dump_c(acc, uC);
    __syncthreads();
    float bb[4], gg[4], nb4[4];
#pragma unroll
    for (int j = 0; j < 4; j++) {
        bb[j] = brel[lane + j * 64];
        gg[j] = n1g[lane + j * 64];
        nb4[j] = n1b[lane + j * 64];
    }
#pragma unroll
    for (int i = 0; i < 8; i++) {
        int row = tn * 8 + i;
        float v[4];
#pragma unroll
        for (int j = 0; j < 4; j++) v[j] = gelu_f(uC[row * 264 + lane + j * 64] + bb[j]);
        float m = wsum64(v[0] + v[1] + v[2] + v[3]) * (1.0f / H);
        float d[4], q = 0.f;
#pragma unroll
        for (int j = 0; j < 4; j++) { d[j] = v[j] - m; q += d[j] * d[j]; }
        float inv = rsqrtf(wsum64(q) * (1.0f / H) + 1e-5f);
        int n = nb + row;
        if (n < N_NODES) {
#pragma unroll
            for (int j = 0; j < 4; j++) {
                size_t idx = (size_t)n * H + lane + j * 64;
                float r = d[j] * inv * gg[j] + nb4[j] + xres[idx];
                x1[idx] = r;
                x1b[idx] = __float2bfloat16(r);
            }
        }
    }
}

// xl = x1@Wl + bl ; xr = x1@Wr + br  (bf16 outs, direct frag stores)
__global__ __launch_bounds__(256) void k_lin2(
        const short* __restrict__ x1b, const short* __restrict__ WlT,
        const short* __restrict__ WrT, const float* __restrict__ bl,
        const float* __restrict__ br, bf16* __restrict__ xlb,
        bf16* __restrict__ xrb) {
    __shared__ short sA[32 * 40];
    __shared__ short sW1[256 * 40];
    __shared__ short sW2[256 * 40];
    int nb = blockIdx.x * 32;
    f4v accL[2][4] = {};
    f4v accR[2][4] = {};
    for (int c = 0; c < 8; c++) {
        stage_a(x1b, nb, c, sA);
        stage_wt(WlT, c, sW1);
        stage_wt(WrT, c, sW2);
        __syncthreads();
        mfma_step(sA, sW1, accL);
        mfma_step(sA, sW2, accR);
        __syncthreads();
    }
    int lane = threadIdx.x & 63, wv = threadIdx.x >> 6;
    int m = lane & 15, quad = lane >> 4;
#pragma unroll
    for (int ctl = 0; ctl < 4; ctl++) {
        int colx = wv * 64 + ctl * 16 + m;
        float blv = bl[colx], brv = br[colx];
#pragma unroll
        for (int r = 0; r < 2; r++)
#pragma unroll
            for (int reg = 0; reg < 4; reg++) {
                int n = nb + r * 16 + quad * 4 + reg;
                if (n < N_NODES) {
                    xlb[(size_t)n * H + colx] = __float2bfloat16(accL[r][ctl][reg] + blv);
                    xrb[(size_t)n * H + colx] = __float2bfloat16(accR[r][ctl][reg] + brv);
                }
            }
    }
}

// fused GATv2 + x2 epilogue — two-pass chunked softmax with dword-typed LDS
// v-cache (fix: consistent unsigned type on both write and read sides, plus
// block barriers at pass boundaries to fence LDS ordering).
__global__ __launch_bounds__(256, 8) void k_gat(
        const int* __restrict__ row, const int* __restrict__ col,
        const bf16* __restrict__ xl, const bf16* __restrict__ xr,
        const float* __restrict__ att, const float* __restrict__ gatb,
        const float* __restrict__ n2g, const float* __restrict__ n2b,
        const float* __restrict__ x1, bf16* __restrict__ x2b) {
    __shared__ unsigned vc[NHEADS][32][33];   // 32 dwords = 64 bf16 dims, pad 33
    __shared__ float slog[NHEADS][32];
    __shared__ float red[8];
    int n = blockIdx.x;
    int tid = threadIdx.x;
    int h = tid >> 6, lane = tid & 63;
    int ei = lane >> 2, dc = lane & 3;
    float xr16[16], att16[16];
    {
        const bf16* xrrow = xr + (size_t)n * H + h * DH + dc * 16;
        const float* attrow = att + h * DH + dc * 16;
#pragma unroll
        for (int j = 0; j < 16; j++) {
            xr16[j] = __bfloat162float(xrrow[j]);
            att16[j] = attrow[j];
        }
    }
    int rs = row[n];
    int ec = row[n + 1] - rs + 1;   // extended: index 0 = self-loop
    float m = -3.4e38f, l = 0.f, acc = 0.f;
    for (int c0 = 0; c0 < ec; c0 += 32) {
        int cnt = min(32, ec - c0);
        // ---- pass 1: logits + LDS v-cache (2 sub-iters of 16 edges) ----
#pragma unroll
        for (int base = 0; base < 32; base += 16) {
            int eidx = base + ei;
            bool valid = eidx < cnt;
            int g = c0 + eidx;
            int s = (valid && g > 0) ? col[rs + g - 1] : n;
            const unsigned* xlr = (const unsigned*)(xl + (size_t)s * H + h * DH + dc * 16);
            unsigned* vrow = &vc[h][eidx][dc * 8];
            float p = 0.f;
#pragma unroll
            for (int jj = 0; jj < 8; jj++) {
                unsigned u = xlr[jj];
                vrow[jj] = u;
                float v0 = __uint_as_float((u & 0xffffu) << 16);
                float v1 = __uint_as_float(u & 0xffff0000u);
                float a0 = v0 + xr16[2 * jj];
                float a1 = v1 + xr16[2 * jj + 1];
                a0 = (a0 > 0.f) ? a0 : 0.2f * a0;
                a1 = (a1 > 0.f) ? a1 : 0.2f * a1;
                p += a0 * att16[2 * jj] + a1 * att16[2 * jj + 1];
            }
            p += __shfl_xor(p, 1, 64);
            p += __shfl_xor(p, 2, 64);
            if (valid && dc == 0) slog[h][eidx] = p;
        }
        __syncthreads();   // fence: v-cache + slog writes complete, pin ordering
        // ---- chunk max (wave-local; cnt <= 32) ----
        float cm = (lane < cnt) ? slog[h][lane] : -3.4e38f;
#pragma unroll
        for (int o = 32; o > 0; o >>= 1) cm = fmaxf(cm, __shfl_xor(cm, o, 64));
        float nm = fmaxf(m, cm);
        float sc = __expf(m - nm);
        l *= sc; acc *= sc; m = nm;
        // ---- pass 2: alpha-weighted accumulation from LDS (lane = dim) ----
        int half = lane & 1;                 // dim = lane; dword = lane>>1
        for (int gi = 0; gi < cnt; gi += 4) {
#pragma unroll
            for (int k = 0; k < 4; k++) {
                int gg = gi + k;
                if (gg < cnt) {
                    float a = __expf(slog[h][gg] - m);
                    unsigned u = vc[h][gg][lane >> 1];
                    float w = __uint_as_float(half ? (u & 0xffff0000u) : (u << 16));
                    l += a;
                    acc += a * w;
                }
            }
        }
        __syncthreads();   // fence: reads done before next chunk overwrites
    }
    // ---- fused x2 epilogue: LN(gelu(msg + gatb)) + x1 ----
    float msg = acc / l;
    int off = tid;
    float p = gelu_f(msg + gatb[off]);
    float sm = blk_sum(p, red) * (1.0f / H);
    float dd = p - sm;
    float vv = blk_sum(dd * dd, red) * (1.0f / H);
    float inv = rsqrtf(vv + 1e-5f);
    float r = dd * inv * n2g[off] + n2b[off] + x1[(size_t)n * H + off];
    x2b[(size_t)n * H + off] = __float2bfloat16(r);
}

// gates via MFMA
__global__ __launch_bounds__(256) void k_gates(
        const short* __restrict__ x2b, const short* __restrict__ Wg2aT,
        const short* __restrict__ Wg1aT, const float* __restrict__ bg2a,
        const float* __restrict__ Wg2b, const float* __restrict__ bg2b,
        const float* __restrict__ bg1a, const float* __restrict__ Wg1b,
        const float* __restrict__ bg1b, float* __restrict__ gate1,
        float* __restrict__ gate2) {
    __shared__ short sA[32 * 40];
    __shared__ float u[12800];
    short* sW2g = (short*)u;
    short* sW1g = sW2g + 10240;
    float* C2 = u;
    float* C1 = u + 8448;
    int nb = blockIdx.x * 32;
    int lane = threadIdx.x & 63, tn = threadIdx.x >> 6;
    f4v acc2[2][4] = {};
    f4v acc1[2][2] = {};
    for (int c = 0; c < 8; c++) {
        stage_a(x2b, nb, c, sA);
        stage_wt(Wg2aT, c, sW2g);
        stage_wt128(Wg1aT, c, sW1g);
        __syncthreads();
        mfma_step(sA, sW2g, acc2);
        mfma_step128(sA, sW1g, acc1);
        __syncthreads();
    }
    dump_c(acc2, C2);
    dump_c128(acc1, C1);
    __syncthreads();
    float wb2[4], b2[4], wb1[2], b1[2];
#pragma unroll
    for (int j = 0; j < 4; j++) { wb2[j] = Wg2b[lane + j * 64]; b2[j] = bg2a[lane + j * 64]; }
#pragma unroll
    for (int j = 0; j < 2; j++) { wb1[j] = Wg1b[lane + j * 64]; b1[j] = bg1a[lane + j * 64]; }
    float c2c = bg2b[0], c1c = bg1b[0];
#pragma unroll
    for (int i = 0; i < 8; i++) {
        int rowi = tn * 8 + i;
        float s2 = 0.f;
#pragma unroll
        for (int j = 0; j < 4; j++) s2 += tanhf(C2[rowi * 264 + lane + j * 64] + b2[j]) * wb2[j];
        s2 = wsum64(s2);
        float s1 = 0.f;
#pragma unroll
        for (int j = 0; j < 2; j++) s1 += tanhf(C1[rowi * 136 + lane + j * 64] + b1[j]) * wb1[j];
        s1 = wsum64(s1);
        int n = nb + rowi;
        if (lane == 0 && n < N_NODES) { gate2[n] = s2 + c2c; gate1[n] = s1 + c1c; }
    }
}

// per-group pooling (x2 read as bf16)
__global__ void k_group(const int* __restrict__ batch, const bf16* __restrict__ x2b,
                        const float* __restrict__ xres, const float* __restrict__ g1,
                        const float* __restrict__ g2, float* __restrict__ gs1,
                        float* __restrict__ gs2, float* __restrict__ fin) {
    __shared__ float red[8];
    __shared__ int seb[2];
    int g = blockIdx.x >> 2, part = blockIdx.x & 3;
    int tid = threadIdx.x;
    if (tid == 0) {
        seb[0] = lowerb(batch, N_NODES, g);
        seb[1] = lowerb(batch, N_NODES, g + 1);
    }
    __syncthreads();
    int s = seb[0], e = seb[1];
    if (e <= s) return;
    float m1 = -3.4e38f, m2 = -3.4e38f;
    for (int i = s + tid; i < e; i += 256) {
        m1 = fmaxf(m1, g1[i]);
        m2 = fmaxf(m2, g2[i]);
    }
    m1 = blk_max(m1, red);
    m2 = blk_max(m2, red);
    int deg = e - s;
    int q0 = s + deg * part / 4, q1 = s + deg * (part + 1) / 4;
    float s1 = 0.f, s2 = 0.f, e1 = 0.f, e2 = 0.f, gr = 0.f;
    for (int i = q0; i < q1; i++) {
        float w1 = __expf(g1[i] - m1);
        float w2 = __expf(g2[i] - m2);
        float xv = __bfloat162float(x2b[(size_t)i * H + tid]);
        float rv = xres[(size_t)i * H + tid];
        s1 += w1; s2 += w2;
        e1 += w1 * xv; e2 += w2 * xv; gr += rv;
    }
    if (q1 > q0) {
        atomicAdd(&fin[(size_t)g * 768 + tid], e1);
        atomicAdd(&fin[(size_t)g * 768 + 256 + tid], e2);
        atomicAdd(&fin[(size_t)g * 768 + 512 + tid], gr);
        if (tid == 0) { atomicAdd(&gs1[g], s1); atomicAdd(&gs2[g], s2); }
    }
}

// out = gelu([emb1|emb2|gres] @ Wo + bo) * bn — grid (NG, 8)
__global__ __launch_bounds__(256) void k_final(
        const int* __restrict__ batch, const float* __restrict__ fin,
        const float* __restrict__ gs1, const float* __restrict__ gs2,
        const float* __restrict__ Wo, const float* __restrict__ bo,
        const float* __restrict__ bng, const float* __restrict__ bnb,
        float* __restrict__ out) {
    __shared__ float fl[768];
    __shared__ float part[4][64];
    __shared__ int seb[2];
    int g = blockIdx.x, oc = blockIdx.y;
    int tid = threadIdx.x, lane = tid & 63, wv = tid >> 6;
    if (tid == 0) {
        seb[0] = lowerb(batch, N_NODES, g);
        seb[1] = lowerb(batch, N_NODES, g + 1);
    }
    __syncthreads();
    float c = fmaxf((float)(seb[1] - seb[0]), 1.0f);
    float s1 = gs1[g], s2 = gs2[g];
    fl[tid]       = (s1 > 0.f) ? fin[(size_t)g * 768 + tid] / s1 : 0.f;
    fl[256 + tid] = (s2 > 0.f) ? fin[(size_t)g * 768 + 256 + tid] / s2 : 0.f;
    fl[512 + tid] = fin[(size_t)g * 768 + 512 + tid] / c;
    __syncthreads();
    int o = oc * 64 + lane;
    float acc = 0.f;
    int k0 = wv * 192;
    for (int k = k0; k < k0 + 192; k += 8) {
#pragma unroll
        for (int j = 0; j < 8; j++)
            acc += fl[k + j] * Wo[(size_t)(k + j) * OUT_DIM + o];
    }
    part[wv][lane] = acc;
    __syncthreads();
    if (wv == 0) {
        float t = part[0][lane] + part[1][lane] + part[2][lane] + part[3][lane] + bo[o];
        float val = gelu_f(t);
        out[(size_t)g * OUT_DIM + o] = val * 0.9999950000374997f * bng[o] + bnb[o];
    }
}

extern "C" void kernel_launch(void* const* d_in, const int* in_sizes, int n_in,
                              void* d_out, int out_size, void* d_ws, size_t ws_size,
                              hipStream_t stream) {
    const float* x     = (const float*)d_in[0];
    const int*   ei    = (const int*)d_in[1];
    const int*   batch = (const int*)d_in[2];
    const float* ln_in_g = (const float*)d_in[3];
    const float* ln_in_b = (const float*)d_in[4];
    const float* Wp    = (const float*)d_in[5];
    const float* bp    = (const float*)d_in[6];
    const float* lnp_g = (const float*)d_in[7];
    const float* lnp_b = (const float*)d_in[8];
    const float* Wrel  = (const float*)d_in[9];
    const float* brel  = (const float*)d_in[10];
    const float* Wroot = (const float*)d_in[11];
    const float* n1_g  = (const float*)d_in[12];
    const float* n1_b  = (const float*)d_in[13];
    const float* Wl    = (const float*)d_in[14];
    const float* bl    = (const float*)d_in[15];
    const float* Wr    = (const float*)d_in[16];
    const float* br    = (const float*)d_in[17];
    const float* att   = (const float*)d_in[18];
    const float* gat_b = (const float*)d_in[19];
    const float* n2_g  = (const float*)d_in[20];
    const float* n2_b  = (const float*)d_in[21];
    const float* Wg1a  = (const float*)d_in[22];
    const float* bg1a  = (const float*)d_in[23];
    const float* Wg1b  = (const float*)d_in[24];
    const float* bg1b  = (const float*)d_in[25];
    const float* Wg2a  = (const float*)d_in[26];
    const float* bg2a  = (const float*)d_in[27];
    const float* Wg2b  = (const float*)d_in[28];
    const float* bg2b  = (const float*)d_in[29];
    const float* Wo    = (const float*)d_in[30];
    const float* bo    = (const float*)d_in[31];
    const float* bn_g  = (const float*)d_in[32];
    const float* bn_b  = (const float*)d_in[33];

    float* ws = (float*)d_ws;
    int* wsi = (int*)d_ws;
    const int* src = ei;
    const int* dst = ei + N_EDGES;
    int* cur = wsi + IOFF_CUR;
    int* row = wsi + IOFF_ROW;
    int* col = wsi + IOFF_COL;
    short* WpT    = (short*)(ws + OFF_WPT);
    short* WrelT  = (short*)(ws + OFF_WRELT);
    short* WrootT = (short*)(ws + OFF_WROOTT);
    short* WlT    = (short*)(ws + OFF_WLT);
    short* WrT    = (short*)(ws + OFF_WRT);
    short* Wg2aT  = (short*)(ws + OFF_WG2AT);
    short* Wg1aT  = (short*)(ws + OFF_WG1AT);
    bf16* xlb   = (bf16*)(ws + OFF_XLB);
    bf16* xrb   = (bf16*)(ws + OFF_XRB);
    bf16* xresb = (bf16*)(ws + OFF_XRESB);
    bf16* aggb  = (bf16*)(ws + OFF_AGGB);
    bf16* x1b   = (bf16*)(ws + OFF_X1B);
    bf16* x2b   = (bf16*)(ws + OFF_X2B);
    const int GB32 = (N_NODES + 31) / 32;  // 313

    hipMemsetAsync(cur, 0, N_NODES * sizeof(int), stream);
    hipMemsetAsync(ws + OFF_GS1, 0, (128 + (size_t)NG * 768) * sizeof(float), stream);
    k_count<<<(N_EDGES + 255) / 256, 256, 0, stream>>>(dst, cur);
    k_scan<<<1, 1024, 0, stream>>>(cur, row);
    hipMemsetAsync(cur, 0, N_NODES * sizeof(int), stream);
    k_fill<<<(N_EDGES + 255) / 256, 256, 0, stream>>>(src, dst, row, cur, col);

    k_twall<<<dim3(16, 4, 7), 256, 0, stream>>>(Wp, Wrel, Wroot, Wl, Wr, Wg2a, Wg1a,
                                                WpT, WrelT, WrootT, WlT, WrT, Wg2aT,
                                                Wg1aT);
    k_proj<<<GB32, 256, 0, stream>>>(x, ln_in_g, ln_in_b, WpT, bp, lnp_g, lnp_b,
                                     ws + OFF_XRES, xresb);
    k_gather<<<N_NODES, 256, 0, stream>>>(row, col, xresb, aggb);
    k_conv<<<GB32, 256, 0, stream>>>((const short*)aggb, (const short*)xresb,
                                     ws + OFF_XRES, WrelT, WrootT, brel, n1_g, n1_b,
                                     ws + OFF_X1, x1b);
    k_lin2<<<GB32, 256, 0, stream>>>((const short*)x1b, WlT, WrT, bl, br, xlb, xrb);
    k_gat<<<N_NODES, 256, 0, stream>>>(row, col, xlb, xrb, att, gat_b, n2_g, n2_b,
                                       ws + OFF_X1, x2b);
    k_gates<<<GB32, 256, 0, stream>>>((const short*)x2b, Wg2aT, Wg1aT, bg2a, Wg2b,
                                      bg2b, bg1a, Wg1b, bg1b, ws + OFF_G1, ws + OFF_G2);
    k_group<<<NG * 4, 256, 0, stream>>>(batch, x2b, ws + OFF_XRES, ws + OFF_G1,
                                        ws + OFF_G2, ws + OFF_GS1, ws + OFF_GS2,
                                        ws + OFF_FIN);
    k_final<<<dim3(NG, 8), 256, 0, stream>>>(batch, ws + OFF_FIN, ws + OFF_GS1,
                                             ws + OFF_GS2, Wo, bo, bn_g, bn_b,
                                             (float*)d_out);
}

// Round 13
// 389.077 us; speedup vs baseline: 1.1558x; 1.0101x over previous
//
#include <hip/hip_runtime.h>
#include <hip/hip_bf16.h>

#define N_NODES 10000
#define N_EDGES 320000
#define DIN 512
#define H 256
#define NHEADS 4
#define DH 64
#define NG 64
#define OUT_DIM 512

typedef __hip_bfloat16 bf16;
typedef __attribute__((ext_vector_type(8))) short s8v;
typedef __attribute__((ext_vector_type(4))) float f4v;

// ---------- workspace layout (float offsets) ----------
static const size_t OFF_XRES  = 0;           // N*H fp32
static const size_t OFF_X1    = 2560000;     // N*H fp32
static const size_t OFF_XLB   = 5120000;     // N*H bf16
static const size_t OFF_XRB   = 6400000;     // N*H bf16
static const size_t OFF_XRESB = 7680000;     // N*H bf16
static const size_t OFF_AGGB  = 8960000;     // N*H bf16
static const size_t OFF_X1B   = 10240000;    // N*H bf16
static const size_t OFF_X2B   = 11520000;    // N*H bf16
static const size_t OFF_WPT   = 12800000;    // 512x256 bf16 (tiled)
static const size_t OFF_WRELT = 12865536;
static const size_t OFF_WROOTT= 12898304;
static const size_t OFF_WLT   = 12931072;
static const size_t OFF_WRT   = 12963840;
static const size_t OFF_WG2AT = 12996608;
static const size_t OFF_WG1AT = 13029376;    // 256x128 bf16 (tiled)
static const size_t OFF_G1    = 13045760;    // N
static const size_t OFF_G2    = 13055760;    // N
static const size_t OFF_GS1   = 13065760;    // 64
static const size_t OFF_GS2   = 13065824;    // 64
static const size_t OFF_FIN   = 13065888;    // G*768
// int offsets into (int*)ws
static const size_t IOFF_CUR  = 13120000;    // N
static const size_t IOFF_ROW  = 13130016;    // N+1
static const size_t IOFF_COL  = 13140032;    // E

__device__ __forceinline__ float gelu_f(float x) {
    return 0.5f * x * (1.0f + erff(x * 0.70710678118654752440f));
}
__device__ __forceinline__ short f2bf(float f) {
    union { float f; unsigned u; } v; v.f = f;
    unsigned r = v.u + 0x7fffu + ((v.u >> 16) & 1u);
    return (short)(r >> 16);
}
__device__ __forceinline__ float wsum64(float v) {
#pragma unroll
    for (int o = 32; o > 0; o >>= 1) v += __shfl_xor(v, o, 64);
    return v;
}
__device__ __forceinline__ float blk_sum(float v, float* s) {
#pragma unroll
    for (int o = 32; o > 0; o >>= 1) v += __shfl_xor(v, o, 64);
    int lane = threadIdx.x & 63, w = threadIdx.x >> 6;
    __syncthreads();
    if (lane == 0) s[w] = v;
    __syncthreads();
    float t = 0.f;
    int nw = blockDim.x >> 6;
    for (int i = 0; i < nw; i++) t += s[i];
    return t;
}
__device__ __forceinline__ float blk_max(float v, float* s) {
#pragma unroll
    for (int o = 32; o > 0; o >>= 1) v = fmaxf(v, __shfl_xor(v, o, 64));
    int lane = threadIdx.x & 63, w = threadIdx.x >> 6;
    __syncthreads();
    if (lane == 0) s[w] = v;
    __syncthreads();
    float t = s[0];
    int nw = blockDim.x >> 6;
    for (int i = 1; i < nw; i++) t = fmaxf(t, s[i]);
    return t;
}
__device__ __forceinline__ int lowerb(const int* b, int n, int v) {
    int lo = 0, hi = n;
    while (lo < hi) { int mid = (lo + hi) >> 1; if (b[mid] < v) lo = mid + 1; else hi = mid; }
    return lo;
}

// ---------- CSR build ----------
__global__ void k_count(const int* __restrict__ dst, int* __restrict__ deg) {
    int e = blockIdx.x * blockDim.x + threadIdx.x;
    if (e < N_EDGES) atomicAdd(&deg[dst[e]], 1);
}
// exclusive scan; also zeroes deg (saves the second memset dispatch)
__global__ void k_scan(int* __restrict__ deg, int* __restrict__ row) {
    __shared__ int part[1024];
    int t = threadIdx.x;
    int base = t * 10;
    int v[10];
    int s = 0;
#pragma unroll
    for (int i = 0; i < 10; i++) {
        int idx = base + i;
        v[i] = (idx < N_NODES) ? deg[idx] : 0;
        if (idx < N_NODES) deg[idx] = 0;
        s += v[i];
    }
    part[t] = s;
    __syncthreads();
    for (int off = 1; off < 1024; off <<= 1) {
        int x = (t >= off) ? part[t - off] : 0;
        __syncthreads();
        part[t] += x;
        __syncthreads();
    }
    int run = (t == 0) ? 0 : part[t - 1];
#pragma unroll
    for (int i = 0; i < 10; i++) {
        int idx = base + i;
        if (idx < N_NODES) row[idx] = run;
        run += v[i];
    }
    if (t == 1023) row[N_NODES] = part[1023];
}
__global__ void k_fill(const int* __restrict__ src, const int* __restrict__ dst,
                       const int* __restrict__ row, int* __restrict__ cur,
                       int* __restrict__ col) {
    int e = blockIdx.x * blockDim.x + threadIdx.x;
    if (e >= N_EDGES) return;
    int d = dst[e];
    int pos = atomicAdd(&cur[d], 1);
    col[row[d] + pos] = src[e];
}

// ---------- weight transpose+cast: W[K][N] fp32 -> Wt tiled [K/32][N][32] bf16 ----------
__global__ void k_twall(const float* Wp, const float* Wrel, const float* Wroot,
                        const float* Wl, const float* Wr, const float* Wg2a,
                        const float* Wg1a, short* WpT, short* WrelT, short* WrootT,
                        short* WlT, short* WrT, short* Wg2aT, short* Wg1aT) {
    const float* W; short* out; int K, N;
    switch (blockIdx.z) {
        case 0: W = Wp;   out = WpT;   K = 512; N = 256; break;
        case 1: W = Wrel; out = WrelT; K = 256; N = 256; break;
        case 2: W = Wroot;out = WrootT;K = 256; N = 256; break;
        case 3: W = Wl;   out = WlT;   K = 256; N = 256; break;
        case 4: W = Wr;   out = WrT;   K = 256; N = 256; break;
        case 5: W = Wg2a; out = Wg2aT; K = 256; N = 256; break;
        default:W = Wg1a; out = Wg1aT; K = 256; N = 128; break;
    }
    int c = blockIdx.x, nb = blockIdx.y * 64;
    if (c * 32 >= K || nb >= N) return;
    __shared__ float t[32][65];
    int tid = threadIdx.x;
    int col = tid & 63, kr = tid >> 6;
#pragma unroll
    for (int i = 0; i < 8; i++) {
        int kk = kr * 8 + i;
        t[kk][col] = W[(size_t)(c * 32 + kk) * N + nb + col];
    }
    __syncthreads();
#pragma unroll
    for (int i = 0; i < 8; i++) {
        int idx = tid + i * 256;
        int nn = idx >> 5, kk = idx & 31;
        out[(size_t)c * N * 32 + (size_t)(nb + nn) * 32 + kk] = f2bf(t[kk][nn]);
    }
}

// ---------- MFMA GEMM building blocks ----------
__device__ __forceinline__ void stage_a(const short* __restrict__ A, int nb, int c,
                                        short* sA) {
    int t = threadIdx.x;
    if (t < 128) {
        int r = t >> 2, part = t & 3;
        int n = nb + r;
        s8v v = {};
        if (n < N_NODES) v = *(const s8v*)(A + (size_t)n * 256 + c * 32 + part * 8);
        *(s8v*)(sA + r * 40 + part * 8) = v;
    }
}
__device__ __forceinline__ void stage_wt(const short* __restrict__ Wt, int c, short* sW) {
    int t = threadIdx.x;
    const s8v* src = (const s8v*)(Wt + (size_t)c * 8192);
#pragma unroll
    for (int i = 0; i < 4; i++) {
        int u = t + i * 256;
        *(s8v*)(sW + (u >> 2) * 40 + (u & 3) * 8) = src[u];
    }
}
__device__ __forceinline__ void stage_wt128(const short* __restrict__ Wt, int c, short* sW) {
    int t = threadIdx.x;
    const s8v* src = (const s8v*)(Wt + (size_t)c * 4096);
#pragma unroll
    for (int i = 0; i < 2; i++) {
        int u = t + i * 256;
        *(s8v*)(sW + (u >> 2) * 40 + (u & 3) * 8) = src[u];
    }
}
__device__ __forceinline__ void mfma_step(const short* sA, const short* sW,
                                          f4v (&acc)[2][4]) {
    int lane = threadIdx.x & 63, wv = threadIdx.x >> 6;
    int m = lane & 15, quad = lane >> 4;
    s8v af0 = *(const s8v*)(sA + m * 40 + quad * 8);
    s8v af1 = *(const s8v*)(sA + (16 + m) * 40 + quad * 8);
#pragma unroll
    for (int ctl = 0; ctl < 4; ctl++) {
        s8v bf = *(const s8v*)(sW + (wv * 64 + ctl * 16 + m) * 40 + quad * 8);
        acc[0][ctl] = __builtin_amdgcn_mfma_f32_16x16x32_bf16(af0, bf, acc[0][ctl], 0, 0, 0);
        acc[1][ctl] = __builtin_amdgcn_mfma_f32_16x16x32_bf16(af1, bf, acc[1][ctl], 0, 0, 0);
    }
}
__device__ __forceinline__ void mfma_step128(const short* sA, const short* sW,
                                             f4v (&acc)[2][2]) {
    int lane = threadIdx.x & 63, wv = threadIdx.x >> 6;
    int m = lane & 15, quad = lane >> 4;
    s8v af0 = *(const s8v*)(sA + m * 40 + quad * 8);
    s8v af1 = *(const s8v*)(sA + (16 + m) * 40 + quad * 8);
#pragma unroll
    for (int ctl = 0; ctl < 2; ctl++) {
        s8v bf = *(const s8v*)(sW + (wv * 32 + ctl * 16 + m) * 40 + quad * 8);
        acc[0][ctl] = __builtin_amdgcn_mfma_f32_16x16x32_bf16(af0, bf, acc[0][ctl], 0, 0, 0);
        acc[1][ctl] = __builtin_amdgcn_mfma_f32_16x16x32_bf16(af1, bf, acc[1][ctl], 0, 0, 0);
    }
}
__device__ __forceinline__ void dump_c(const f4v (&acc)[2][4], float* C) {
    int lane = threadIdx.x & 63, wv = threadIdx.x >> 6;
    int m = lane & 15, quad = lane >> 4;
#pragma unroll
    for (int r = 0; r < 2; r++)
#pragma unroll
        for (int ctl = 0; ctl < 4; ctl++)
#pragma unroll
            for (int reg = 0; reg < 4; reg++)
                C[(r * 16 + quad * 4 + reg) * 264 + wv * 64 + ctl * 16 + m] = acc[r][ctl][reg];
}
__device__ __forceinline__ void dump_c128(const f4v (&acc)[2][2], float* C) {
    int lane = threadIdx.x & 63, wv = threadIdx.x >> 6;
    int m = lane & 15, quad = lane >> 4;
#pragma unroll
    for (int r = 0; r < 2; r++)
#pragma unroll
        for (int ctl = 0; ctl < 2; ctl++)
#pragma unroll
            for (int reg = 0; reg < 4; reg++)
                C[(r * 16 + quad * 4 + reg) * 136 + wv * 32 + ctl * 16 + m] = acc[r][ctl][reg];
}

// ---------- kernels ----------

// x_res = LN(gelu(LN_in(x) @ Wp + bp))
__global__ __launch_bounds__(256) void k_proj(
        const float* __restrict__ x, const float* __restrict__ g0,
        const float* __restrict__ b0, const short* __restrict__ WpT,
        const float* __restrict__ bp, const float* __restrict__ lg,
        const float* __restrict__ lb, float* __restrict__ xres,
        bf16* __restrict__ xresb) {
    __shared__ short sA[32 * 40];
    __shared__ float uC[32 * 264];      // union: sW (20 KB) overlays C (33 KB)
    short* sW = (short*)uC;
    __shared__ float sm_mean[32], sm_invs[32];
    int nb = blockIdx.x * 32;
    int lane = threadIdx.x & 63, tn = threadIdx.x >> 6;
#pragma unroll
    for (int i = 0; i < 8; i++) {
        int r = tn * 8 + i;
        int n = nb + r;
        float s = 0.f, q = 0.f;
        if (n < N_NODES) {
#pragma unroll
            for (int j = 0; j < 8; j++) {
                float v = x[(size_t)n * DIN + lane + j * 64];
                s += v; q += v * v;
            }
        }
        s = wsum64(s); q = wsum64(q);
        float m = s * (1.0f / DIN);
        float var = q * (1.0f / DIN) - m * m;
        if (lane == 0) { sm_mean[r] = m; sm_invs[r] = rsqrtf(var + 1e-5f); }
    }
    __syncthreads();
    f4v acc[2][4] = {};
    for (int c = 0; c < 16; c++) {
        int t = threadIdx.x;
        if (t < 128) {
            int r = t >> 2, part = t & 3;
            int n = nb + r;
            short tmp[8];
            if (n < N_NODES) {
                int k = c * 32 + part * 8;
                float mm = sm_mean[r], is = sm_invs[r];
#pragma unroll
                for (int jj = 0; jj < 8; jj++) {
                    float v = (x[(size_t)n * DIN + k + jj] - mm) * is * g0[k + jj] + b0[k + jj];
                    tmp[jj] = f2bf(v);
                }
            } else {
#pragma unroll
                for (int jj = 0; jj < 8; jj++) tmp[jj] = 0;
            }
            *(s8v*)(sA + r * 40 + part * 8) = *(s8v*)tmp;
        }
        stage_wt(WpT, c, sW);
        __syncthreads();
        mfma_step(sA, sW, acc);
        __syncthreads();
    }
    dump_c(acc, uC);
    __syncthreads();
    float bp4[4], lg4[4], lb4[4];
#pragma unroll
    for (int j = 0; j < 4; j++) {
        bp4[j] = bp[lane + j * 64];
        lg4[j] = lg[lane + j * 64];
        lb4[j] = lb[lane + j * 64];
    }
#pragma unroll
    for (int i = 0; i < 8; i++) {
        int row = tn * 8 + i;
        float v[4];
#pragma unroll
        for (int j = 0; j < 4; j++) v[j] = gelu_f(uC[row * 264 + lane + j * 64] + bp4[j]);
        float m = wsum64(v[0] + v[1] + v[2] + v[3]) * (1.0f / H);
        float d[4], q = 0.f;
#pragma unroll
        for (int j = 0; j < 4; j++) { d[j] = v[j] - m; q += d[j] * d[j]; }
        float inv = rsqrtf(wsum64(q) * (1.0f / H) + 1e-5f);
        int n = nb + row;
        if (n < N_NODES) {
#pragma unroll
            for (int j = 0; j < 4; j++) {
                float r = d[j] * inv * lg4[j] + lb4[j];
                xres[(size_t)n * H + lane + j * 64] = r;
                xresb[(size_t)n * H + lane + j * 64] = __float2bfloat16(r);
            }
        }
    }
}

// aggb[n] = bf16( sum_{s in nbrs(n)} xresb[s] )
__global__ void k_gather(const int* __restrict__ row, const int* __restrict__ col,
                         const bf16* __restrict__ xresb, bf16* __restrict__ aggb) {
    int n = blockIdx.x, tid = threadIdx.x;
    int i = row[n], e0 = row[n + 1];
    float a = 0.f;
    for (; i + 7 < e0; i += 8) {
        int c0 = col[i], c1 = col[i + 1], c2 = col[i + 2], c3 = col[i + 3];
        int c4 = col[i + 4], c5 = col[i + 5], c6 = col[i + 6], c7 = col[i + 7];
        a += __bfloat162float(xresb[(size_t)c0 * H + tid])
           + __bfloat162float(xresb[(size_t)c1 * H + tid])
           + __bfloat162float(xresb[(size_t)c2 * H + tid])
           + __bfloat162float(xresb[(size_t)c3 * H + tid])
           + __bfloat162float(xresb[(size_t)c4 * H + tid])
           + __bfloat162float(xresb[(size_t)c5 * H + tid])
           + __bfloat162float(xresb[(size_t)c6 * H + tid])
           + __bfloat162float(xresb[(size_t)c7 * H + tid]);
    }
    for (; i < e0; i++) a += __bfloat162float(xresb[(size_t)col[i] * H + tid]);
    aggb[(size_t)n * H + tid] = __float2bfloat16(a);
}

// x1 = LN(gelu(agg@Wrel + xres@Wroot + brel)) + xres ; also x1b bf16
__global__ __launch_bounds__(256) void k_conv(
        const short* __restrict__ aggb, const short* __restrict__ xresbS,
        const float* __restrict__ xres, const short* __restrict__ WrelT,
        const short* __restrict__ WrootT, const float* __restrict__ brel,
        const float* __restrict__ n1g, const float* __restrict__ n1b,
        float* __restrict__ x1, bf16* __restrict__ x1b) {
    __shared__ short sA1[32 * 40];
    __shared__ short sA2[32 * 40];
    __shared__ float uC[32 * 264 + 2048];   // union: sW1+sW2 / C
    short* sW1 = (short*)uC;
    short* sW2 = sW1 + 10240;
    int nb = blockIdx.x * 32;
    int lane = threadIdx.x & 63, tn = threadIdx.x >> 6;
    f4v acc[2][4] = {};
    for (int c = 0; c < 8; c++) {
        stage_a(aggb, nb, c, sA1);
        stage_a(xresbS, nb, c, sA2);
        stage_wt(WrelT, c, sW1);
        stage_wt(WrootT, c, sW2);
        __syncthreads();
        mfma_step(sA1, sW1, acc);
        mfma_step(sA2, sW2, acc);
        __syncthreads();
    }
    dump_c(acc, uC);
    __syncthreads();
    float bb[4], gg[4], nb4[4];
#pragma unroll
    for (int j = 0; j < 4; j++) {
        bb[j] = brel[lane + j * 64];
        gg[j] = n1g[lane + j * 64];
        nb4[j] = n1b[lane + j * 64];
    }
#pragma unroll
    for (int i = 0; i < 8; i++) {
        int row = tn * 8 + i;
        float v[4];
#pragma unroll
        for (int j = 0; j < 4; j++) v[j] = gelu_f(uC[row * 264 + lane + j * 64] + bb[j]);
        float m = wsum64(v[0] + v[1] + v[2] + v[3]) * (1.0f / H);
        float d[4], q = 0.f;
#pragma unroll
        for (int j = 0; j < 4; j++) { d[j] = v[j] - m; q += d[j] * d[j]; }
        float inv = rsqrtf(wsum64(q) * (1.0f / H) + 1e-5f);
        int n = nb + row;
        if (n < N_NODES) {
#pragma unroll
            for (int j = 0; j < 4; j++) {
                size_t idx = (size_t)n * H + lane + j * 64;
                float r = d[j] * inv * gg[j] + nb4[j] + xres[idx];
                x1[idx] = r;
                x1b[idx] = __float2bfloat16(r);
            }
        }
    }
}

// xl = x1@Wl + bl ; xr = x1@Wr + br  (bf16 outs, direct frag stores)
__global__ __launch_bounds__(256) void k_lin2(
        const short* __restrict__ x1b, const short* __restrict__ WlT,
        const short* __restrict__ WrT, const float* __restrict__ bl,
        const float* __restrict__ br, bf16* __restrict__ xlb,
        bf16* __restrict__ xrb) {
    __shared__ short sA[32 * 40];
    __shared__ short sW1[256 * 40];
    __shared__ short sW2[256 * 40];
    int nb = blockIdx.x * 32;
    f4v accL[2][4] = {};
    f4v accR[2][4] = {};
    for (int c = 0; c < 8; c++) {
        stage_a(x1b, nb, c, sA);
        stage_wt(WlT, c, sW1);
        stage_wt(WrT, c, sW2);
        __syncthreads();
        mfma_step(sA, sW1, accL);
        mfma_step(sA, sW2, accR);
        __syncthreads();
    }
    int lane = threadIdx.x & 63, wv = threadIdx.x >> 6;
    int m = lane & 15, quad = lane >> 4;
#pragma unroll
    for (int ctl = 0; ctl < 4; ctl++) {
        int colx = wv * 64 + ctl * 16 + m;
        float blv = bl[colx], brv = br[colx];
#pragma unroll
        for (int r = 0; r < 2; r++)
#pragma unroll
            for (int reg = 0; reg < 4; reg++) {
                int n = nb + r * 16 + quad * 4 + reg;
                if (n < N_NODES) {
                    xlb[(size_t)n * H + colx] = __float2bfloat16(accL[r][ctl][reg] + blv);
                    xrb[(size_t)n * H + colx] = __float2bfloat16(accR[r][ctl][reg] + brv);
                }
            }
    }
}

// fused GATv2 + x2 epilogue — two-pass chunked softmax with dword LDS v-cache.
// R13: alphas computed once per chunk (1 exp/lane, wave-reduced l), pass 2 is
// pure LDS-read + FMA.
__global__ __launch_bounds__(256, 8) void k_gat(
        const int* __restrict__ row, const int* __restrict__ col,
        const bf16* __restrict__ xl, const bf16* __restrict__ xr,
        const float* __restrict__ att, const float* __restrict__ gatb,
        const float* __restrict__ n2g, const float* __restrict__ n2b,
        const float* __restrict__ x1, bf16* __restrict__ x2b) {
    __shared__ unsigned vc[NHEADS][32][33];   // 32 dwords = 64 bf16 dims, pad 33
    __shared__ float slog[NHEADS][32];        // logits, then alphas
    __shared__ float red[8];
    int n = blockIdx.x;
    int tid = threadIdx.x;
    int h = tid >> 6, lane = tid & 63;
    int ei = lane >> 2, dc = lane & 3;
    float xr16[16], att16[16];
    {
        const bf16* xrrow = xr + (size_t)n * H + h * DH + dc * 16;
        const float* attrow = att + h * DH + dc * 16;
#pragma unroll
        for (int j = 0; j < 16; j++) {
            xr16[j] = __bfloat162float(xrrow[j]);
            att16[j] = attrow[j];
        }
    }
    int rs = row[n];
    int ec = row[n + 1] - rs + 1;   // extended: index 0 = self-loop
    float m = -3.4e38f, l = 0.f, acc = 0.f;
    int shamt = (lane & 1) * 16;    // bf16 half select for pass 2
    for (int c0 = 0; c0 < ec; c0 += 32) {
        int cnt = min(32, ec - c0);
        // ---- pass 1: logits + LDS v-cache (2 sub-iters of 16 edges) ----
#pragma unroll
        for (int base = 0; base < 32; base += 16) {
            int eidx = base + ei;
            bool valid = eidx < cnt;
            int g = c0 + eidx;
            int s = (valid && g > 0) ? col[rs + g - 1] : n;
            const unsigned* xlr = (const unsigned*)(xl + (size_t)s * H + h * DH + dc * 16);
            unsigned* vrow = &vc[h][eidx][dc * 8];
            float p = 0.f;
#pragma unroll
            for (int jj = 0; jj < 8; jj++) {
                unsigned u = xlr[jj];
                vrow[jj] = u;
                float v0 = __uint_as_float((u & 0xffffu) << 16);
                float v1 = __uint_as_float(u & 0xffff0000u);
                float a0 = v0 + xr16[2 * jj];
                float a1 = v1 + xr16[2 * jj + 1];
                a0 = fmaxf(a0, 0.2f * a0);   // leaky relu (slope<1)
                a1 = fmaxf(a1, 0.2f * a1);
                p += a0 * att16[2 * jj] + a1 * att16[2 * jj + 1];
            }
            p += __shfl_xor(p, 1, 64);
            p += __shfl_xor(p, 2, 64);
            if (valid && dc == 0) slog[h][eidx] = p;
        }
        __syncthreads();   // fence: v-cache + slog writes complete
        // ---- chunk max + alpha precompute (one exp per edge, wave-wide l) ----
        float p_lane = (lane < cnt) ? slog[h][lane] : -3.4e38f;
        float cm = p_lane;
#pragma unroll
        for (int o = 32; o > 0; o >>= 1) cm = fmaxf(cm, __shfl_xor(cm, o, 64));
        float nm = fmaxf(m, cm);
        float sc = __expf(m - nm);
        float a_lane = (lane < cnt) ? __expf(p_lane - nm) : 0.f;
        l = l * sc + wsum64(a_lane);
        acc *= sc;
        m = nm;
        if (lane < cnt) slog[h][lane] = a_lane;   // overwrite logits with alphas
        // ---- pass 2: alpha-weighted accumulation from LDS (lane = dim) ----
        for (int gi = 0; gi < cnt; gi += 4) {
#pragma unroll
            for (int k = 0; k < 4; k++) {
                int gg = gi + k;
                if (gg < cnt) {
                    float a = slog[h][gg];                    // broadcast read
                    unsigned u = vc[h][gg][lane >> 1];
                    float w = __uint_as_float((u >> shamt) << 16);
                    acc += a * w;
                }
            }
        }
        __syncthreads();   // fence: reads done before next chunk overwrites
    }
    // ---- fused x2 epilogue: LN(gelu(msg + gatb)) + x1 ----
    float msg = acc / l;
    int off = tid;
    float p = gelu_f(msg + gatb[off]);
    float sm = blk_sum(p, red) * (1.0f / H);
    float dd = p - sm;
    float vv = blk_sum(dd * dd, red) * (1.0f / H);
    float inv = rsqrtf(vv + 1e-5f);
    float r = dd * inv * n2g[off] + n2b[off] + x1[(size_t)n * H + off];
    x2b[(size_t)n * H + off] = __float2bfloat16(r);
}

// gates via MFMA
__global__ __launch_bounds__(256) void k_gates(
        const short* __restrict__ x2b, const short* __restrict__ Wg2aT,
        const short* __restrict__ Wg1aT, const float* __restrict__ bg2a,
        const float* __restrict__ Wg2b, const float* __restrict__ bg2b,
        const float* __restrict__ bg1a, const float* __restrict__ Wg1b,
        const float* __restrict__ bg1b, float* __restrict__ gate1,
        float* __restrict__ gate2) {
    __shared__ short sA[32 * 40];
    __shared__ float u[12800];
    short* sW2g = (short*)u;
    short* sW1g = sW2g + 10240;
    float* C2 = u;
    float* C1 = u + 8448;
    int nb = blockIdx.x * 32;
    int lane = threadIdx.x & 63, tn = threadIdx.x >> 6;
    f4v acc2[2][4] = {};
    f4v acc1[2][2] = {};
    for (int c = 0; c < 8; c++) {
        stage_a(x2b, nb, c, sA);
        stage_wt(Wg2aT, c, sW2g);
        stage_wt128(Wg1aT, c, sW1g);
        __syncthreads();
        mfma_step(sA, sW2g, acc2);
        mfma_step128(sA, sW1g, acc1);
        __syncthreads();
    }
    dump_c(acc2, C2);
    dump_c128(acc1, C1);
    __syncthreads();
    float wb2[4], b2[4], wb1[2], b1[2];
#pragma unroll
    for (int j = 0; j < 4; j++) { wb2[j] = Wg2b[lane + j * 64]; b2[j] = bg2a[lane + j * 64]; }
#pragma unroll
    for (int j = 0; j < 2; j++) { wb1[j] = Wg1b[lane + j * 64]; b1[j] = bg1a[lane + j * 64]; }
    float c2c = bg2b[0], c1c = bg1b[0];
#pragma unroll
    for (int i = 0; i < 8; i++) {
        int rowi = tn * 8 + i;
        float s2 = 0.f;
#pragma unroll
        for (int j = 0; j < 4; j++) s2 += tanhf(C2[rowi * 264 + lane + j * 64] + b2[j]) * wb2[j];
        s2 = wsum64(s2);
        float s1 = 0.f;
#pragma unroll
        for (int j = 0; j < 2; j++) s1 += tanhf(C1[rowi * 136 + lane + j * 64] + b1[j]) * wb1[j];
        s1 = wsum64(s1);
        int n = nb + rowi;
        if (lane == 0 && n < N_NODES) { gate2[n] = s2 + c2c; gate1[n] = s1 + c1c; }
    }
}

// per-group pooling (x2 read as bf16)
__global__ void k_group(const int* __restrict__ batch, const bf16* __restrict__ x2b,
                        const float* __restrict__ xres, const float* __restrict__ g1,
                        const float* __restrict__ g2, float* __restrict__ gs1,
                        float* __restrict__ gs2, float* __restrict__ fin) {
    __shared__ float red[8];
    __shared__ int seb[2];
    int g = blockIdx.x >> 2, part = blockIdx.x & 3;
    int tid = threadIdx.x;
    if (tid == 0) {
        seb[0] = lowerb(batch, N_NODES, g);
        seb[1] = lowerb(batch, N_NODES, g + 1);
    }
    __syncthreads();
    int s = seb[0], e = seb[1];
    if (e <= s) return;
    float m1 = -3.4e38f, m2 = -3.4e38f;
    for (int i = s + tid; i < e; i += 256) {
        m1 = fmaxf(m1, g1[i]);
        m2 = fmaxf(m2, g2[i]);
    }
    m1 = blk_max(m1, red);
    m2 = blk_max(m2, red);
    int deg = e - s;
    int q0 = s + deg * part / 4, q1 = s + deg * (part + 1) / 4;
    float s1 = 0.f, s2 = 0.f, e1 = 0.f, e2 = 0.f, gr = 0.f;
    for (int i = q0; i < q1; i++) {
        float w1 = __expf(g1[i] - m1);
        float w2 = __expf(g2[i] - m2);
        float xv = __bfloat162float(x2b[(size_t)i * H + tid]);
        float rv = xres[(size_t)i * H + tid];
        s1 += w1; s2 += w2;
        e1 += w1 * xv; e2 += w2 * xv; gr += rv;
    }
    if (q1 > q0) {
        atomicAdd(&fin[(size_t)g * 768 + tid], e1);
        atomicAdd(&fin[(size_t)g * 768 + 256 + tid], e2);
        atomicAdd(&fin[(size_t)g * 768 + 512 + tid], gr);
        if (tid == 0) { atomicAdd(&gs1[g], s1); atomicAdd(&gs2[g], s2); }
    }
}

// out = gelu([emb1|emb2|gres] @ Wo + bo) * bn — grid (NG, 8)
__global__ __launch_bounds__(256) void k_final(
        const int* __restrict__ batch, const float* __restrict__ fin,
        const float* __restrict__ gs1, const float* __restrict__ gs2,
        const float* __restrict__ Wo, const float* __restrict__ bo,
        const float* __restrict__ bng, const float* __restrict__ bnb,
        float* __restrict__ out) {
    __shared__ float fl[768];
    __shared__ float part[4][64];
    __shared__ int seb[2];
    int g = blockIdx.x, oc = blockIdx.y;
    int tid = threadIdx.x, lane = tid & 63, wv = tid >> 6;
    if (tid == 0) {
        seb[0] = lowerb(batch, N_NODES, g);
        seb[1] = lowerb(batch, N_NODES, g + 1);
    }
    __syncthreads();
    float c = fmaxf((float)(seb[1] - seb[0]), 1.0f);
    float s1 = gs1[g], s2 = gs2[g];
    fl[tid]       = (s1 > 0.f) ? fin[(size_t)g * 768 + tid] / s1 : 0.f;
    fl[256 + tid] = (s2 > 0.f) ? fin[(size_t)g * 768 + 256 + tid] / s2 : 0.f;
    fl[512 + tid] = fin[(size_t)g * 768 + 512 + tid] / c;
    __syncthreads();
    int o = oc * 64 + lane;
    float acc = 0.f;
    int k0 = wv * 192;
    for (int k = k0; k < k0 + 192; k += 8) {
#pragma unroll
        for (int j = 0; j < 8; j++)
            acc += fl[k + j] * Wo[(size_t)(k + j) * OUT_DIM + o];
    }
    part[wv][lane] = acc;
    __syncthreads();
    if (wv == 0) {
        float t = part[0][lane] + part[1][lane] + part[2][lane] + part[3][lane] + bo[o];
        float val = gelu_f(t);
        out[(size_t)g * OUT_DIM + o] = val * 0.9999950000374997f * bng[o] + bnb[o];
    }
}

extern "C" void kernel_launch(void* const* d_in, const int* in_sizes, int n_in,
                              void* d_out, int out_size, void* d_ws, size_t ws_size,
                              hipStream_t stream) {
    const float* x     = (const float*)d_in[0];
    const int*   ei    = (const int*)d_in[1];
    const int*   batch = (const int*)d_in[2];
    const float* ln_in_g = (const float*)d_in[3];
    const float* ln_in_b = (const float*)d_in[4];
    const float* Wp    = (const float*)d_in[5];
    const float* bp    = (const float*)d_in[6];
    const float* lnp_g = (const float*)d_in[7];
    const float* lnp_b = (const float*)d_in[8];
    const float* Wrel  = (const float*)d_in[9];
    const float* brel  = (const float*)d_in[10];
    const float* Wroot = (const float*)d_in[11];
    const float* n1_g  = (const float*)d_in[12];
    const float* n1_b  = (const float*)d_in[13];
    const float* Wl    = (const float*)d_in[14];
    const float* bl    = (const float*)d_in[15];
    const float* Wr    = (const float*)d_in[16];
    const float* br    = (const float*)d_in[17];
    const float* att   = (const float*)d_in[18];
    const float* gat_b = (const float*)d_in[19];
    const float* n2_g  = (const float*)d_in[20];
    const float* n2_b  = (const float*)d_in[21];
    const float* Wg1a  = (const float*)d_in[22];
    const float* bg1a  = (const float*)d_in[23];
    const float* Wg1b  = (const float*)d_in[24];
    const float* bg1b  = (const float*)d_in[25];
    const float* Wg2a  = (const float*)d_in[26];
    const float* bg2a  = (const float*)d_in[27];
    const float* Wg2b  = (const float*)d_in[28];
    const float* bg2b  = (const float*)d_in[29];
    const float* Wo    = (const float*)d_in[30];
    const float* bo    = (const float*)d_in[31];
    const float* bn_g  = (const float*)d_in[32];
    const float* bn_b  = (const float*)d_in[33];

    float* ws = (float*)d_ws;
    int* wsi = (int*)d_ws;
    const int* src = ei;
    const int* dst = ei + N_EDGES;
    int* cur = wsi + IOFF_CUR;
    int* row = wsi + IOFF_ROW;
    int* col = wsi + IOFF_COL;
    short* WpT    = (short*)(ws + OFF_WPT);
    short* WrelT  = (short*)(ws + OFF_WRELT);
    short* WrootT = (short*)(ws + OFF_WROOTT);
    short* WlT    = (short*)(ws + OFF_WLT);
    short* WrT    = (short*)(ws + OFF_WRT);
    short* Wg2aT  = (short*)(ws + OFF_WG2AT);
    short* Wg1aT  = (short*)(ws + OFF_WG1AT);
    bf16* xlb   = (bf16*)(ws + OFF_XLB);
    bf16* xrb   = (bf16*)(ws + OFF_XRB);
    bf16* xresb = (bf16*)(ws + OFF_XRESB);
    bf16* aggb  = (bf16*)(ws + OFF_AGGB);
    bf16* x1b   = (bf16*)(ws + OFF_X1B);
    bf16* x2b   = (bf16*)(ws + OFF_X2B);
    const int GB32 = (N_NODES + 31) / 32;  // 313

    hipMemsetAsync(cur, 0, N_NODES * sizeof(int), stream);
    hipMemsetAsync(ws + OFF_GS1, 0, (128 + (size_t)NG * 768) * sizeof(float), stream);
    k_count<<<(N_EDGES + 255) / 256, 256, 0, stream>>>(dst, cur);
    k_scan<<<1, 1024, 0, stream>>>(cur, row);   // also zeroes cur
    k_fill<<<(N_EDGES + 255) / 256, 256, 0, stream>>>(src, dst, row, cur, col);

    k_twall<<<dim3(16, 4, 7), 256, 0, stream>>>(Wp, Wrel, Wroot, Wl, Wr, Wg2a, Wg1a,
                                                WpT, WrelT, WrootT, WlT, WrT, Wg2aT,
                                                Wg1aT);
    k_proj<<<GB32, 256, 0, stream>>>(x, ln_in_g, ln_in_b, WpT, bp, lnp_g, lnp_b,
                                     ws + OFF_XRES, xresb);
    k_gather<<<N_NODES, 256, 0, stream>>>(row, col, xresb, aggb);
    k_conv<<<GB32, 256, 0, stream>>>((const short*)aggb, (const short*)xresb,
                                     ws + OFF_XRES, WrelT, WrootT, brel, n1_g, n1_b,
                                     ws + OFF_X1, x1b);
    k_lin2<<<GB32, 256, 0, stream>>>((const short*)x1b, WlT, WrT, bl, br, xlb, xrb);
    k_gat<<<N_NODES, 256, 0, stream>>>(row, col, xlb, xrb, att, gat_b, n2_g, n2_b,
                                       ws + OFF_X1, x2b);
    k_gates<<<GB32, 256, 0, stream>>>((const short*)x2b, Wg2aT, Wg1aT, bg2a, Wg2b,
                                      bg2b, bg1a, Wg1b, bg1b, ws + OFF_G1, ws + OFF_G2);
    k_group<<<NG * 4, 256, 0, stream>>>(batch, x2b, ws + OFF_XRES, ws + OFF_G1,
                                        ws + OFF_G2, ws + OFF_GS1, ws + OFF_GS2,
                                        ws + OFF_FIN);
    k_final<<<dim3(NG, 8), 256, 0, stream>>>(batch, ws + OFF_FIN, ws + OFF_GS1,
                                             ws + OFF_GS2, Wo, bo, bn_g, bn_b,
                                             (float*)d_out);
}

// Round 14
// 370.752 us; speedup vs baseline: 1.2130x; 1.0494x over previous
//
#include <hip/hip_runtime.h>
#include <hip/hip_bf16.h>

#define N_NODES 10000
#define N_EDGES 320000
#define DIN 512
#define H 256
#define NHEADS 4
#define DH 64
#define NG 64
#define OUT_DIM 512

typedef __hip_bfloat16 bf16;
typedef __attribute__((ext_vector_type(8))) short s8v;
typedef __attribute__((ext_vector_type(4))) float f4v;

// ---------- workspace layout (float offsets) ----------
static const size_t OFF_XRES  = 0;           // N*H fp32
static const size_t OFF_X1    = 2560000;     // N*H fp32
static const size_t OFF_XLB   = 5120000;     // N*H bf16
static const size_t OFF_XRB   = 6400000;     // N*H bf16
static const size_t OFF_XRESB = 7680000;     // N*H bf16
static const size_t OFF_AGGB  = 8960000;     // N*H bf16
static const size_t OFF_X1B   = 10240000;    // N*H bf16
static const size_t OFF_X2B   = 11520000;    // N*H bf16
static const size_t OFF_WPT   = 12800000;    // 512x256 bf16 (tiled)
static const size_t OFF_WRELT = 12865536;
static const size_t OFF_WROOTT= 12898304;
static const size_t OFF_WLT   = 12931072;
static const size_t OFF_WRT   = 12963840;
static const size_t OFF_WG2AT = 12996608;
static const size_t OFF_WG1AT = 13029376;    // 256x128 bf16 (tiled)
static const size_t OFF_G1    = 13045760;    // N
static const size_t OFF_G2    = 13055760;    // N
static const size_t OFF_GS1   = 13065760;    // 64
static const size_t OFF_GS2   = 13065824;    // 64
static const size_t OFF_FIN   = 13065888;    // G*768
// int offsets into (int*)ws
static const size_t IOFF_CUR  = 13120000;    // N
static const size_t IOFF_ROW  = 13130016;    // N+1
static const size_t IOFF_COL  = 13140032;    // E

__device__ __forceinline__ float gelu_f(float x) {
    return 0.5f * x * (1.0f + erff(x * 0.70710678118654752440f));
}
__device__ __forceinline__ short f2bf(float f) {
    union { float f; unsigned u; } v; v.f = f;
    unsigned r = v.u + 0x7fffu + ((v.u >> 16) & 1u);
    return (short)(r >> 16);
}
__device__ __forceinline__ float wsum64(float v) {
#pragma unroll
    for (int o = 32; o > 0; o >>= 1) v += __shfl_xor(v, o, 64);
    return v;
}
__device__ __forceinline__ float blk_sum(float v, float* s) {
#pragma unroll
    for (int o = 32; o > 0; o >>= 1) v += __shfl_xor(v, o, 64);
    int lane = threadIdx.x & 63, w = threadIdx.x >> 6;
    __syncthreads();
    if (lane == 0) s[w] = v;
    __syncthreads();
    float t = 0.f;
    int nw = blockDim.x >> 6;
    for (int i = 0; i < nw; i++) t += s[i];
    return t;
}
__device__ __forceinline__ float blk_max(float v, float* s) {
#pragma unroll
    for (int o = 32; o > 0; o >>= 1) v = fmaxf(v, __shfl_xor(v, o, 64));
    int lane = threadIdx.x & 63, w = threadIdx.x >> 6;
    __syncthreads();
    if (lane == 0) s[w] = v;
    __syncthreads();
    float t = s[0];
    int nw = blockDim.x >> 6;
    for (int i = 1; i < nw; i++) t = fmaxf(t, s[i]);
    return t;
}
__device__ __forceinline__ int lowerb(const int* b, int n, int v) {
    int lo = 0, hi = n;
    while (lo < hi) { int mid = (lo + hi) >> 1; if (b[mid] < v) lo = mid + 1; else hi = mid; }
    return lo;
}

// ---------- CSR build ----------
__global__ void k_count(const int* __restrict__ dst, int* __restrict__ deg) {
    int e = blockIdx.x * blockDim.x + threadIdx.x;
    if (e < N_EDGES) atomicAdd(&deg[dst[e]], 1);
}
// exclusive scan; also zeroes deg
__global__ void k_scan(int* __restrict__ deg, int* __restrict__ row) {
    __shared__ int part[1024];
    int t = threadIdx.x;
    int base = t * 10;
    int v[10];
    int s = 0;
#pragma unroll
    for (int i = 0; i < 10; i++) {
        int idx = base + i;
        v[i] = (idx < N_NODES) ? deg[idx] : 0;
        if (idx < N_NODES) deg[idx] = 0;
        s += v[i];
    }
    part[t] = s;
    __syncthreads();
    for (int off = 1; off < 1024; off <<= 1) {
        int x = (t >= off) ? part[t - off] : 0;
        __syncthreads();
        part[t] += x;
        __syncthreads();
    }
    int run = (t == 0) ? 0 : part[t - 1];
#pragma unroll
    for (int i = 0; i < 10; i++) {
        int idx = base + i;
        if (idx < N_NODES) row[idx] = run;
        run += v[i];
    }
    if (t == 1023) row[N_NODES] = part[1023];
}
__global__ void k_fill(const int* __restrict__ src, const int* __restrict__ dst,
                       const int* __restrict__ row, int* __restrict__ cur,
                       int* __restrict__ col) {
    int e = blockIdx.x * blockDim.x + threadIdx.x;
    if (e >= N_EDGES) return;
    int d = dst[e];
    int pos = atomicAdd(&cur[d], 1);
    col[row[d] + pos] = src[e];
}

// ---------- weight transpose+cast: W[K][N] fp32 -> Wt tiled [K/32][N][32] bf16 ----------
__global__ void k_twall(const float* Wp, const float* Wrel, const float* Wroot,
                        const float* Wl, const float* Wr, const float* Wg2a,
                        const float* Wg1a, short* WpT, short* WrelT, short* WrootT,
                        short* WlT, short* WrT, short* Wg2aT, short* Wg1aT) {
    const float* W; short* out; int K, N;
    switch (blockIdx.z) {
        case 0: W = Wp;   out = WpT;   K = 512; N = 256; break;
        case 1: W = Wrel; out = WrelT; K = 256; N = 256; break;
        case 2: W = Wroot;out = WrootT;K = 256; N = 256; break;
        case 3: W = Wl;   out = WlT;   K = 256; N = 256; break;
        case 4: W = Wr;   out = WrT;   K = 256; N = 256; break;
        case 5: W = Wg2a; out = Wg2aT; K = 256; N = 256; break;
        default:W = Wg1a; out = Wg1aT; K = 256; N = 128; break;
    }
    int c = blockIdx.x, nb = blockIdx.y * 64;
    if (c * 32 >= K || nb >= N) return;
    __shared__ float t[32][65];
    int tid = threadIdx.x;
    int col = tid & 63, kr = tid >> 6;
#pragma unroll
    for (int i = 0; i < 8; i++) {
        int kk = kr * 8 + i;
        t[kk][col] = W[(size_t)(c * 32 + kk) * N + nb + col];
    }
    __syncthreads();
#pragma unroll
    for (int i = 0; i < 8; i++) {
        int idx = tid + i * 256;
        int nn = idx >> 5, kk = idx & 31;
        out[(size_t)c * N * 32 + (size_t)(nb + nn) * 32 + kk] = f2bf(t[kk][nn]);
    }
}

// ---------- MFMA GEMM building blocks (512-thread / 8-wave blocks) ----------
// Tile: 32 rows x 256 cols; wave wv owns cols {wv*32 + ctl*16}, ctl in {0,1}.
__device__ __forceinline__ void stage_a(const short* __restrict__ A, int nb, int c,
                                        short* sA) {
    int t = threadIdx.x;
    if (t < 128) {
        int r = t >> 2, part = t & 3;
        int n = nb + r;
        s8v v = {};
        if (n < N_NODES) v = *(const s8v*)(A + (size_t)n * 256 + c * 32 + part * 8);
        *(s8v*)(sA + r * 40 + part * 8) = v;
    }
}
__device__ __forceinline__ void stage_wt(const short* __restrict__ Wt, int c, short* sW) {
    int t = threadIdx.x;   // 512 threads, 1024 s8v elements
    const s8v* src = (const s8v*)(Wt + (size_t)c * 8192);
#pragma unroll
    for (int i = 0; i < 2; i++) {
        int u = t + i * 512;
        *(s8v*)(sW + (u >> 2) * 40 + (u & 3) * 8) = src[u];
    }
}
__device__ __forceinline__ void stage_wt128(const short* __restrict__ Wt, int c, short* sW) {
    int t = threadIdx.x;   // 512 threads, 512 s8v elements
    const s8v* src = (const s8v*)(Wt + (size_t)c * 4096);
    *(s8v*)(sW + (t >> 2) * 40 + (t & 3) * 8) = src[t];
}
__device__ __forceinline__ void mfma_step(const short* sA, const short* sW,
                                          f4v (&acc)[2][2]) {
    int lane = threadIdx.x & 63, wv = threadIdx.x >> 6;   // wv in [0,8)
    int m = lane & 15, quad = lane >> 4;
    s8v af0 = *(const s8v*)(sA + m * 40 + quad * 8);
    s8v af1 = *(const s8v*)(sA + (16 + m) * 40 + quad * 8);
#pragma unroll
    for (int ctl = 0; ctl < 2; ctl++) {
        s8v bf = *(const s8v*)(sW + (wv * 32 + ctl * 16 + m) * 40 + quad * 8);
        acc[0][ctl] = __builtin_amdgcn_mfma_f32_16x16x32_bf16(af0, bf, acc[0][ctl], 0, 0, 0);
        acc[1][ctl] = __builtin_amdgcn_mfma_f32_16x16x32_bf16(af1, bf, acc[1][ctl], 0, 0, 0);
    }
}
__device__ __forceinline__ void mfma_step128(const short* sA, const short* sW,
                                             f4v (&acc)[2]) {
    int lane = threadIdx.x & 63, wv = threadIdx.x >> 6;
    int m = lane & 15, quad = lane >> 4;
    s8v af0 = *(const s8v*)(sA + m * 40 + quad * 8);
    s8v af1 = *(const s8v*)(sA + (16 + m) * 40 + quad * 8);
    s8v bf = *(const s8v*)(sW + (wv * 16 + m) * 40 + quad * 8);
    acc[0] = __builtin_amdgcn_mfma_f32_16x16x32_bf16(af0, bf, acc[0], 0, 0, 0);
    acc[1] = __builtin_amdgcn_mfma_f32_16x16x32_bf16(af1, bf, acc[1], 0, 0, 0);
}
__device__ __forceinline__ void dump_c(const f4v (&acc)[2][2], float* C) {
    int lane = threadIdx.x & 63, wv = threadIdx.x >> 6;
    int m = lane & 15, quad = lane >> 4;
#pragma unroll
    for (int r = 0; r < 2; r++)
#pragma unroll
        for (int ctl = 0; ctl < 2; ctl++)
#pragma unroll
            for (int reg = 0; reg < 4; reg++)
                C[(r * 16 + quad * 4 + reg) * 264 + wv * 32 + ctl * 16 + m] = acc[r][ctl][reg];
}
__device__ __forceinline__ void dump_c128(const f4v (&acc)[2], float* C) {
    int lane = threadIdx.x & 63, wv = threadIdx.x >> 6;
    int m = lane & 15, quad = lane >> 4;
#pragma unroll
    for (int r = 0; r < 2; r++)
#pragma unroll
        for (int reg = 0; reg < 4; reg++)
            C[(r * 16 + quad * 4 + reg) * 136 + wv * 16 + m] = acc[r][reg];
}

// ---------- kernels ----------

// x_res = LN(gelu(LN_in(x) @ Wp + bp))   [512 threads]
__global__ __launch_bounds__(512) void k_proj(
        const float* __restrict__ x, const float* __restrict__ g0,
        const float* __restrict__ b0, const short* __restrict__ WpT,
        const float* __restrict__ bp, const float* __restrict__ lg,
        const float* __restrict__ lb, float* __restrict__ xres,
        bf16* __restrict__ xresb) {
    __shared__ short sA[32 * 40];
    __shared__ float uC[32 * 264];      // union: sW (20 KB) overlays C (33 KB)
    short* sW = (short*)uC;
    __shared__ float sm_mean[32], sm_invs[32];
    int nb = blockIdx.x * 32;
    int lane = threadIdx.x & 63, tn = threadIdx.x >> 6;  // tn in [0,8)
#pragma unroll
    for (int i = 0; i < 4; i++) {
        int r = tn * 4 + i;
        int n = nb + r;
        float s = 0.f, q = 0.f;
        if (n < N_NODES) {
#pragma unroll
            for (int j = 0; j < 8; j++) {
                float v = x[(size_t)n * DIN + lane + j * 64];
                s += v; q += v * v;
            }
        }
        s = wsum64(s); q = wsum64(q);
        float m = s * (1.0f / DIN);
        float var = q * (1.0f / DIN) - m * m;
        if (lane == 0) { sm_mean[r] = m; sm_invs[r] = rsqrtf(var + 1e-5f); }
    }
    __syncthreads();
    f4v acc[2][2] = {};
    for (int c = 0; c < 16; c++) {
        int t = threadIdx.x;
        if (t < 128) {
            int r = t >> 2, part = t & 3;
            int n = nb + r;
            short tmp[8];
            if (n < N_NODES) {
                int k = c * 32 + part * 8;
                float mm = sm_mean[r], is = sm_invs[r];
#pragma unroll
                for (int jj = 0; jj < 8; jj++) {
                    float v = (x[(size_t)n * DIN + k + jj] - mm) * is * g0[k + jj] + b0[k + jj];
                    tmp[jj] = f2bf(v);
                }
            } else {
#pragma unroll
                for (int jj = 0; jj < 8; jj++) tmp[jj] = 0;
            }
            *(s8v*)(sA + r * 40 + part * 8) = *(s8v*)tmp;
        }
        stage_wt(WpT, c, sW);
        __syncthreads();
        mfma_step(sA, sW, acc);
        __syncthreads();
    }
    dump_c(acc, uC);
    __syncthreads();
    float bp4[4], lg4[4], lb4[4];
#pragma unroll
    for (int j = 0; j < 4; j++) {
        bp4[j] = bp[lane + j * 64];
        lg4[j] = lg[lane + j * 64];
        lb4[j] = lb[lane + j * 64];
    }
#pragma unroll
    for (int i = 0; i < 4; i++) {
        int row = tn * 4 + i;
        float v[4];
#pragma unroll
        for (int j = 0; j < 4; j++) v[j] = gelu_f(uC[row * 264 + lane + j * 64] + bp4[j]);
        float m = wsum64(v[0] + v[1] + v[2] + v[3]) * (1.0f / H);
        float d[4], q = 0.f;
#pragma unroll
        for (int j = 0; j < 4; j++) { d[j] = v[j] - m; q += d[j] * d[j]; }
        float inv = rsqrtf(wsum64(q) * (1.0f / H) + 1e-5f);
        int n = nb + row;
        if (n < N_NODES) {
#pragma unroll
            for (int j = 0; j < 4; j++) {
                float r = d[j] * inv * lg4[j] + lb4[j];
                xres[(size_t)n * H + lane + j * 64] = r;
                xresb[(size_t)n * H + lane + j * 64] = __float2bfloat16(r);
            }
        }
    }
}

// aggb[n] = bf16( sum_{s in nbrs(n)} xresb[s] )
__global__ void k_gather(const int* __restrict__ row, const int* __restrict__ col,
                         const bf16* __restrict__ xresb, bf16* __restrict__ aggb) {
    int n = blockIdx.x, tid = threadIdx.x;
    int i = row[n], e0 = row[n + 1];
    float a = 0.f;
    for (; i + 7 < e0; i += 8) {
        int c0 = col[i], c1 = col[i + 1], c2 = col[i + 2], c3 = col[i + 3];
        int c4 = col[i + 4], c5 = col[i + 5], c6 = col[i + 6], c7 = col[i + 7];
        a += __bfloat162float(xresb[(size_t)c0 * H + tid])
           + __bfloat162float(xresb[(size_t)c1 * H + tid])
           + __bfloat162float(xresb[(size_t)c2 * H + tid])
           + __bfloat162float(xresb[(size_t)c3 * H + tid])
           + __bfloat162float(xresb[(size_t)c4 * H + tid])
           + __bfloat162float(xresb[(size_t)c5 * H + tid])
           + __bfloat162float(xresb[(size_t)c6 * H + tid])
           + __bfloat162float(xresb[(size_t)c7 * H + tid]);
    }
    for (; i < e0; i++) a += __bfloat162float(xresb[(size_t)col[i] * H + tid]);
    aggb[(size_t)n * H + tid] = __float2bfloat16(a);
}

// x1 = LN(gelu(agg@Wrel + xres@Wroot + brel)) + xres ; also x1b bf16  [512 thr]
__global__ __launch_bounds__(512) void k_conv(
        const short* __restrict__ aggb, const short* __restrict__ xresbS,
        const float* __restrict__ xres, const short* __restrict__ WrelT,
        const short* __restrict__ WrootT, const float* __restrict__ brel,
        const float* __restrict__ n1g, const float* __restrict__ n1b,
        float* __restrict__ x1, bf16* __restrict__ x1b) {
    __shared__ short sA1[32 * 40];
    __shared__ short sA2[32 * 40];
    __shared__ float uC[32 * 264 + 2048];   // union: sW1+sW2 / C
    short* sW1 = (short*)uC;
    short* sW2 = sW1 + 10240;
    int nb = blockIdx.x * 32;
    int lane = threadIdx.x & 63, tn = threadIdx.x >> 6;
    f4v acc[2][2] = {};
    for (int c = 0; c < 8; c++) {
        stage_a(aggb, nb, c, sA1);
        stage_a(xresbS, nb, c, sA2);
        stage_wt(WrelT, c, sW1);
        stage_wt(WrootT, c, sW2);
        __syncthreads();
        mfma_step(sA1, sW1, acc);
        mfma_step(sA2, sW2, acc);
        __syncthreads();
    }
    dump_c(acc, uC);
    __syncthreads();
    float bb[4], gg[4], nb4[4];
#pragma unroll
    for (int j = 0; j < 4; j++) {
        bb[j] = brel[lane + j * 64];
        gg[j] = n1g[lane + j * 64];
        nb4[j] = n1b[lane + j * 64];
    }
#pragma unroll
    for (int i = 0; i < 4; i++) {
        int row = tn * 4 + i;
        float v[4];
#pragma unroll
        for (int j = 0; j < 4; j++) v[j] = gelu_f(uC[row * 264 + lane + j * 64] + bb[j]);
        float m = wsum64(v[0] + v[1] + v[2] + v[3]) * (1.0f / H);
        float d[4], q = 0.f;
#pragma unroll
        for (int j = 0; j < 4; j++) { d[j] = v[j] - m; q += d[j] * d[j]; }
        float inv = rsqrtf(wsum64(q) * (1.0f / H) + 1e-5f);
        int n = nb + row;
        if (n < N_NODES) {
#pragma unroll
            for (int j = 0; j < 4; j++) {
                size_t idx = (size_t)n * H + lane + j * 64;
                float r = d[j] * inv * gg[j] + nb4[j] + xres[idx];
                x1[idx] = r;
                x1b[idx] = __float2bfloat16(r);
            }
        }
    }
}

// xl = x1@Wl + bl ; xr = x1@Wr + br   [512 thr]
__global__ __launch_bounds__(512) void k_lin2(
        const short* __restrict__ x1b, const short* __restrict__ WlT,
        const short* __restrict__ WrT, const float* __restrict__ bl,
        const float* __restrict__ br, bf16* __restrict__ xlb,
        bf16* __restrict__ xrb) {
    __shared__ short sA[32 * 40];
    __shared__ short sW1[256 * 40];
    __shared__ short sW2[256 * 40];
    int nb = blockIdx.x * 32;
    f4v accL[2][2] = {};
    f4v accR[2][2] = {};
    for (int c = 0; c < 8; c++) {
        stage_a(x1b, nb, c, sA);
        stage_wt(WlT, c, sW1);
        stage_wt(WrT, c, sW2);
        __syncthreads();
        mfma_step(sA, sW1, accL);
        mfma_step(sA, sW2, accR);
        __syncthreads();
    }
    int lane = threadIdx.x & 63, wv = threadIdx.x >> 6;
    int m = lane & 15, quad = lane >> 4;
#pragma unroll
    for (int ctl = 0; ctl < 2; ctl++) {
        int colx = wv * 32 + ctl * 16 + m;
        float blv = bl[colx], brv = br[colx];
#pragma unroll
        for (int r = 0; r < 2; r++)
#pragma unroll
            for (int reg = 0; reg < 4; reg++) {
                int n = nb + r * 16 + quad * 4 + reg;
                if (n < N_NODES) {
                    xlb[(size_t)n * H + colx] = __float2bfloat16(accL[r][ctl][reg] + blv);
                    xrb[(size_t)n * H + colx] = __float2bfloat16(accR[r][ctl][reg] + brv);
                }
            }
    }
}

// fused GATv2 + x2 epilogue — two-pass chunked softmax with dword LDS v-cache.
__global__ __launch_bounds__(256, 8) void k_gat(
        const int* __restrict__ row, const int* __restrict__ col,
        const bf16* __restrict__ xl, const bf16* __restrict__ xr,
        const float* __restrict__ att, const float* __restrict__ gatb,
        const float* __restrict__ n2g, const float* __restrict__ n2b,
        const float* __restrict__ x1, bf16* __restrict__ x2b) {
    __shared__ unsigned vc[NHEADS][32][33];
    __shared__ float slog[NHEADS][32];
    __shared__ float red[8];
    int n = blockIdx.x;
    int tid = threadIdx.x;
    int h = tid >> 6, lane = tid & 63;
    int ei = lane >> 2, dc = lane & 3;
    float xr16[16], att16[16];
    {
        const bf16* xrrow = xr + (size_t)n * H + h * DH + dc * 16;
        const float* attrow = att + h * DH + dc * 16;
#pragma unroll
        for (int j = 0; j < 16; j++) {
            xr16[j] = __bfloat162float(xrrow[j]);
            att16[j] = attrow[j];
        }
    }
    int rs = row[n];
    int ec = row[n + 1] - rs + 1;
    float m = -3.4e38f, l = 0.f, acc = 0.f;
    int shamt = (lane & 1) * 16;
    for (int c0 = 0; c0 < ec; c0 += 32) {
        int cnt = min(32, ec - c0);
#pragma unroll
        for (int base = 0; base < 32; base += 16) {
            int eidx = base + ei;
            bool valid = eidx < cnt;
            int g = c0 + eidx;
            int s = (valid && g > 0) ? col[rs + g - 1] : n;
            const unsigned* xlr = (const unsigned*)(xl + (size_t)s * H + h * DH + dc * 16);
            unsigned* vrow = &vc[h][eidx][dc * 8];
            float p = 0.f;
#pragma unroll
            for (int jj = 0; jj < 8; jj++) {
                unsigned u = xlr[jj];
                vrow[jj] = u;
                float v0 = __uint_as_float((u & 0xffffu) << 16);
                float v1 = __uint_as_float(u & 0xffff0000u);
                float a0 = v0 + xr16[2 * jj];
                float a1 = v1 + xr16[2 * jj + 1];
                a0 = fmaxf(a0, 0.2f * a0);
                a1 = fmaxf(a1, 0.2f * a1);
                p += a0 * att16[2 * jj] + a1 * att16[2 * jj + 1];
            }
            p += __shfl_xor(p, 1, 64);
            p += __shfl_xor(p, 2, 64);
            if (valid && dc == 0) slog[h][eidx] = p;
        }
        __syncthreads();
        float p_lane = (lane < cnt) ? slog[h][lane] : -3.4e38f;
        float cm = p_lane;
#pragma unroll
        for (int o = 32; o > 0; o >>= 1) cm = fmaxf(cm, __shfl_xor(cm, o, 64));
        float nm = fmaxf(m, cm);
        float sc = __expf(m - nm);
        float a_lane = (lane < cnt) ? __expf(p_lane - nm) : 0.f;
        l = l * sc + wsum64(a_lane);
        acc *= sc;
        m = nm;
        if (lane < cnt) slog[h][lane] = a_lane;
        for (int gi = 0; gi < cnt; gi += 4) {
#pragma unroll
            for (int k = 0; k < 4; k++) {
                int gg = gi + k;
                if (gg < cnt) {
                    float a = slog[h][gg];
                    unsigned u = vc[h][gg][lane >> 1];
                    float w = __uint_as_float((u >> shamt) << 16);
                    acc += a * w;
                }
            }
        }
        __syncthreads();
    }
    float msg = acc / l;
    int off = tid;
    float p = gelu_f(msg + gatb[off]);
    float sm = blk_sum(p, red) * (1.0f / H);
    float dd = p - sm;
    float vv = blk_sum(dd * dd, red) * (1.0f / H);
    float inv = rsqrtf(vv + 1e-5f);
    float r = dd * inv * n2g[off] + n2b[off] + x1[(size_t)n * H + off];
    x2b[(size_t)n * H + off] = __float2bfloat16(r);
}

// gates via MFMA  [512 thr]
__global__ __launch_bounds__(512) void k_gates(
        const short* __restrict__ x2b, const short* __restrict__ Wg2aT,
        const short* __restrict__ Wg1aT, const float* __restrict__ bg2a,
        const float* __restrict__ Wg2b, const float* __restrict__ bg2b,
        const float* __restrict__ bg1a, const float* __restrict__ Wg1b,
        const float* __restrict__ bg1b, float* __restrict__ gate1,
        float* __restrict__ gate2) {
    __shared__ short sA[32 * 40];
    __shared__ float u[12800];
    short* sW2g = (short*)u;
    short* sW1g = sW2g + 10240;
    float* C2 = u;
    float* C1 = u + 8448;
    int nb = blockIdx.x * 32;
    int lane = threadIdx.x & 63, tn = threadIdx.x >> 6;
    f4v acc2[2][2] = {};
    f4v acc1[2] = {};
    for (int c = 0; c < 8; c++) {
        stage_a(x2b, nb, c, sA);
        stage_wt(Wg2aT, c, sW2g);
        stage_wt128(Wg1aT, c, sW1g);
        __syncthreads();
        mfma_step(sA, sW2g, acc2);
        mfma_step128(sA, sW1g, acc1);
        __syncthreads();
    }
    dump_c(acc2, C2);
    dump_c128(acc1, C1);
    __syncthreads();
    float wb2[4], b2[4], wb1[2], b1[2];
#pragma unroll
    for (int j = 0; j < 4; j++) { wb2[j] = Wg2b[lane + j * 64]; b2[j] = bg2a[lane + j * 64]; }
#pragma unroll
    for (int j = 0; j < 2; j++) { wb1[j] = Wg1b[lane + j * 64]; b1[j] = bg1a[lane + j * 64]; }
    float c2c = bg2b[0], c1c = bg1b[0];
#pragma unroll
    for (int i = 0; i < 4; i++) {
        int rowi = tn * 4 + i;
        float s2 = 0.f;
#pragma unroll
        for (int j = 0; j < 4; j++) s2 += tanhf(C2[rowi * 264 + lane + j * 64] + b2[j]) * wb2[j];
        s2 = wsum64(s2);
        float s1 = 0.f;
#pragma unroll
        for (int j = 0; j < 2; j++) s1 += tanhf(C1[rowi * 136 + lane + j * 64] + b1[j]) * wb1[j];
        s1 = wsum64(s1);
        int n = nb + rowi;
        if (lane == 0 && n < N_NODES) { gate2[n] = s2 + c2c; gate1[n] = s1 + c1c; }
    }
}

// per-group pooling (x2 read as bf16)
__global__ void k_group(const int* __restrict__ batch, const bf16* __restrict__ x2b,
                        const float* __restrict__ xres, const float* __restrict__ g1,
                        const float* __restrict__ g2, float* __restrict__ gs1,
                        float* __restrict__ gs2, float* __restrict__ fin) {
    __shared__ float red[8];
    __shared__ int seb[2];
    int g = blockIdx.x >> 2, part = blockIdx.x & 3;
    int tid = threadIdx.x;
    if (tid == 0) {
        seb[0] = lowerb(batch, N_NODES, g);
        seb[1] = lowerb(batch, N_NODES, g + 1);
    }
    __syncthreads();
    int s = seb[0], e = seb[1];
    if (e <= s) return;
    float m1 = -3.4e38f, m2 = -3.4e38f;
    for (int i = s + tid; i < e; i += 256) {
        m1 = fmaxf(m1, g1[i]);
        m2 = fmaxf(m2, g2[i]);
    }
    m1 = blk_max(m1, red);
    m2 = blk_max(m2, red);
    int deg = e - s;
    int q0 = s + deg * part / 4, q1 = s + deg * (part + 1) / 4;
    float s1 = 0.f, s2 = 0.f, e1 = 0.f, e2 = 0.f, gr = 0.f;
    for (int i = q0; i < q1; i++) {
        float w1 = __expf(g1[i] - m1);
        float w2 = __expf(g2[i] - m2);
        float xv = __bfloat162float(x2b[(size_t)i * H + tid]);
        float rv = xres[(size_t)i * H + tid];
        s1 += w1; s2 += w2;
        e1 += w1 * xv; e2 += w2 * xv; gr += rv;
    }
    if (q1 > q0) {
        atomicAdd(&fin[(size_t)g * 768 + tid], e1);
        atomicAdd(&fin[(size_t)g * 768 + 256 + tid], e2);
        atomicAdd(&fin[(size_t)g * 768 + 512 + tid], gr);
        if (tid == 0) { atomicAdd(&gs1[g], s1); atomicAdd(&gs2[g], s2); }
    }
}

// out = gelu([emb1|emb2|gres] @ Wo + bo) * bn — grid (NG, 8)
__global__ __launch_bounds__(256) void k_final(
        const int* __restrict__ batch, const float* __restrict__ fin,
        const float* __restrict__ gs1, const float* __restrict__ gs2,
        const float* __restrict__ Wo, const float* __restrict__ bo,
        const float* __restrict__ bng, const float* __restrict__ bnb,
        float* __restrict__ out) {
    __shared__ float fl[768];
    __shared__ float part[4][64];
    __shared__ int seb[2];
    int g = blockIdx.x, oc = blockIdx.y;
    int tid = threadIdx.x, lane = tid & 63, wv = tid >> 6;
    if (tid == 0) {
        seb[0] = lowerb(batch, N_NODES, g);
        seb[1] = lowerb(batch, N_NODES, g + 1);
    }
    __syncthreads();
    float c = fmaxf((float)(seb[1] - seb[0]), 1.0f);
    float s1 = gs1[g], s2 = gs2[g];
    fl[tid]       = (s1 > 0.f) ? fin[(size_t)g * 768 + tid] / s1 : 0.f;
    fl[256 + tid] = (s2 > 0.f) ? fin[(size_t)g * 768 + 256 + tid] / s2 : 0.f;
    fl[512 + tid] = fin[(size_t)g * 768 + 512 + tid] / c;
    __syncthreads();
    int o = oc * 64 + lane;
    float acc = 0.f;
    int k0 = wv * 192;
    for (int k = k0; k < k0 + 192; k += 8) {
#pragma unroll
        for (int j = 0; j < 8; j++)
            acc += fl[k + j] * Wo[(size_t)(k + j) * OUT_DIM + o];
    }
    part[wv][lane] = acc;
    __syncthreads();
    if (wv == 0) {
        float t = part[0][lane] + part[1][lane] + part[2][lane] + part[3][lane] + bo[o];
        float val = gelu_f(t);
        out[(size_t)g * OUT_DIM + o] = val * 0.9999950000374997f * bng[o] + bnb[o];
    }
}

extern "C" void kernel_launch(void* const* d_in, const int* in_sizes, int n_in,
                              void* d_out, int out_size, void* d_ws, size_t ws_size,
                              hipStream_t stream) {
    const float* x     = (const float*)d_in[0];
    const int*   ei    = (const int*)d_in[1];
    const int*   batch = (const int*)d_in[2];
    const float* ln_in_g = (const float*)d_in[3];
    const float* ln_in_b = (const float*)d_in[4];
    const float* Wp    = (const float*)d_in[5];
    const float* bp    = (const float*)d_in[6];
    const float* lnp_g = (const float*)d_in[7];
    const float* lnp_b = (const float*)d_in[8];
    const float* Wrel  = (const float*)d_in[9];
    const float* brel  = (const float*)d_in[10];
    const float* Wroot = (const float*)d_in[11];
    const float* n1_g  = (const float*)d_in[12];
    const float* n1_b  = (const float*)d_in[13];
    const float* Wl    = (const float*)d_in[14];
    const float* bl    = (const float*)d_in[15];
    const float* Wr    = (const float*)d_in[16];
    const float* br    = (const float*)d_in[17];
    const float* att   = (const float*)d_in[18];
    const float* gat_b = (const float*)d_in[19];
    const float* n2_g  = (const float*)d_in[20];
    const float* n2_b  = (const float*)d_in[21];
    const float* Wg1a  = (const float*)d_in[22];
    const float* bg1a  = (const float*)d_in[23];
    const float* Wg1b  = (const float*)d_in[24];
    const float* bg1b  = (const float*)d_in[25];
    const float* Wg2a  = (const float*)d_in[26];
    const float* bg2a  = (const float*)d_in[27];
    const float* Wg2b  = (const float*)d_in[28];
    const float* bg2b  = (const float*)d_in[29];
    const float* Wo    = (const float*)d_in[30];
    const float* bo    = (const float*)d_in[31];
    const float* bn_g  = (const float*)d_in[32];
    const float* bn_b  = (const float*)d_in[33];

    float* ws = (float*)d_ws;
    int* wsi = (int*)d_ws;
    const int* src = ei;
    const int* dst = ei + N_EDGES;
    int* cur = wsi + IOFF_CUR;
    int* row = wsi + IOFF_ROW;
    int* col = wsi + IOFF_COL;
    short* WpT    = (short*)(ws + OFF_WPT);
    short* WrelT  = (short*)(ws + OFF_WRELT);
    short* WrootT = (short*)(ws + OFF_WROOTT);
    short* WlT    = (short*)(ws + OFF_WLT);
    short* WrT    = (short*)(ws + OFF_WRT);
    short* Wg2aT  = (short*)(ws + OFF_WG2AT);
    short* Wg1aT  = (short*)(ws + OFF_WG1AT);
    bf16* xlb   = (bf16*)(ws + OFF_XLB);
    bf16* xrb   = (bf16*)(ws + OFF_XRB);
    bf16* xresb = (bf16*)(ws + OFF_XRESB);
    bf16* aggb  = (bf16*)(ws + OFF_AGGB);
    bf16* x1b   = (bf16*)(ws + OFF_X1B);
    bf16* x2b   = (bf16*)(ws + OFF_X2B);
    const int GB32 = (N_NODES + 31) / 32;  // 313

    hipMemsetAsync(cur, 0, N_NODES * sizeof(int), stream);
    hipMemsetAsync(ws + OFF_GS1, 0, (128 + (size_t)NG * 768) * sizeof(float), stream);
    k_count<<<(N_EDGES + 255) / 256, 256, 0, stream>>>(dst, cur);
    k_scan<<<1, 1024, 0, stream>>>(cur, row);   // also zeroes cur
    k_fill<<<(N_EDGES + 255) / 256, 256, 0, stream>>>(src, dst, row, cur, col);

    k_twall<<<dim3(16, 4, 7), 256, 0, stream>>>(Wp, Wrel, Wroot, Wl, Wr, Wg2a, Wg1a,
                                                WpT, WrelT, WrootT, WlT, WrT, Wg2aT,
                                                Wg1aT);
    k_proj<<<GB32, 512, 0, stream>>>(x, ln_in_g, ln_in_b, WpT, bp, lnp_g, lnp_b,
                                     ws + OFF_XRES, xresb);
    k_gather<<<N_NODES, 256, 0, stream>>>(row, col, xresb, aggb);
    k_conv<<<GB32, 512, 0, stream>>>((const short*)aggb, (const short*)xresb,
                                     ws + OFF_XRES, WrelT, WrootT, brel, n1_g, n1_b,
                                     ws + OFF_X1, x1b);
    k_lin2<<<GB32, 512, 0, stream>>>((const short*)x1b, WlT, WrT, bl, br, xlb, xrb);
    k_gat<<<N_NODES, 256, 0, stream>>>(row, col, xlb, xrb, att, gat_b, n2_g, n2_b,
                                       ws + OFF_X1, x2b);
    k_gates<<<GB32, 512, 0, stream>>>((const short*)x2b, Wg2aT, Wg1aT, bg2a, Wg2b,
                                      bg2b, bg1a, Wg1b, bg1b, ws + OFF_G1, ws + OFF_G2);
    k_group<<<NG * 4, 256, 0, stream>>>(batch, x2b, ws + OFF_XRES, ws + OFF_G1,
                                        ws + OFF_G2, ws + OFF_GS1, ws + OFF_GS2,
                                        ws + OFF_FIN);
    k_final<<<dim3(NG, 8), 256, 0, stream>>>(batch, ws + OFF_FIN, ws + OFF_GS1,
                                             ws + OFF_GS2, Wo, bo, bn_g, bn_b,
                                             (float*)d_out);
}